// Round 1
// baseline (437.605 us; speedup 1.0000x reference)
//
#include <hip/hip_runtime.h>

#define N_NODES 16384
#define N_EDGES 131072
#define DB 2048
#define DF 512

// ---- workspace layout (float offsets) ----
#define WS_STATS 0                      // 8 floats (5 used)
#define WS_PAR   8                      // 256 floats: a,b,c,u0,ub,uf @ +0,+32,+64,+96,+128,+160; consts @ +192..195
#define WS_P0    512
#define WS_PB    (WS_P0 + N_NODES)
#define WS_PF    (WS_PB + N_NODES)
#define WS_DEGB  (WS_PF + N_NODES)
#define WS_DEGF  (WS_DEGB + N_NODES)
#define WS_ACC   (WS_DEGF + N_NODES)
#define WS_SIMB  (WS_ACC + N_NODES)
#define WS_SIMF  (WS_SIMB + N_EDGES)
// total = 512 + 6*N + 2*E floats ~= 1.4 MB

__global__ void k_init(float* __restrict__ ws) {
    int i = blockIdx.x * blockDim.x + threadIdx.x;
    if (i < 8) ws[WS_STATS + i] = 0.f;
    if (i < N_NODES) {
        ws[WS_DEGB + i] = 1.f;   // self-loop weight
        ws[WS_DEGF + i] = 1.f;
        ws[WS_ACC  + i] = 0.f;
    }
}

__global__ void k_stats(const float* __restrict__ x, float* __restrict__ ws) {
    float s0 = 0.f, s1 = 0.f, s2 = 0.f, s3 = 0.f, s4 = 0.f;
    for (int i = blockIdx.x * blockDim.x + threadIdx.x; i < N_NODES;
         i += gridDim.x * blockDim.x) {
        float2 v = ((const float2*)x)[i];
        s0 += v.x; s1 += v.y;
        s2 += v.x * v.x; s3 += v.y * v.y; s4 += v.x * v.y;
    }
    for (int off = 32; off; off >>= 1) {
        s0 += __shfl_down(s0, off);
        s1 += __shfl_down(s1, off);
        s2 += __shfl_down(s2, off);
        s3 += __shfl_down(s3, off);
        s4 += __shfl_down(s4, off);
    }
    if ((threadIdx.x & 63) == 0) {
        atomicAdd(&ws[WS_STATS + 0], s0);
        atomicAdd(&ws[WS_STATS + 1], s1);
        atomicAdd(&ws[WS_STATS + 2], s2);
        atomicAdd(&ws[WS_STATS + 3], s3);
        atomicAdd(&ws[WS_STATS + 4], s4);
    }
}

__global__ void k_params(const float* __restrict__ w1, const float* __restrict__ b1,
                         const float* __restrict__ gamma, const float* __restrict__ beta,
                         const float* __restrict__ w2, const float* __restrict__ b2,
                         const float* __restrict__ w0w, const float* __restrict__ w0b,
                         const float* __restrict__ gbw, const float* __restrict__ gbb,
                         const float* __restrict__ gfw, const float* __restrict__ gfb,
                         const float* __restrict__ wbw, const float* __restrict__ wbb,
                         const float* __restrict__ wfw, const float* __restrict__ wfb,
                         float* __restrict__ ws) {
    const float inv_n = 1.0f / (float)N_NODES;
    float S0 = ws[WS_STATS+0], S1 = ws[WS_STATS+1], S2 = ws[WS_STATS+2],
          S3 = ws[WS_STATS+3], S4 = ws[WS_STATS+4];
    float m0 = S0 * inv_n, m1 = S1 * inv_n;
    float v0 = S2 * inv_n - m0 * m0;
    float v1 = S3 * inv_n - m1 * m1;
    float cv = S4 * inv_n - m0 * m1;
    float* par = ws + WS_PAR;
    int j = threadIdx.x;
    if (j < 32) {
        float W0 = w1[j], W1 = w1[32 + j];
        float mu  = m0 * W0 + m1 * W1 + b1[j];
        float var = W0 * W0 * v0 + W1 * W1 * v1 + 2.f * W0 * W1 * cv;
        float is  = rsqrtf(var + 1e-5f) * gamma[j];
        par[j]      = W0 * is;
        par[32 + j] = W1 * is;
        par[64 + j] = (b1[j] - mu) * is + beta[j];
        float u0 = 0.f, ub = 0.f, uf = 0.f;
        for (int k = 0; k < 32; k++) {
            float w2jk = w2[j * 32 + k];
            float vbk = 0.f, vfk = 0.f;
            for (int n = 0; n < 32; n++) {
                vbk += gbw[k * 32 + n] * wbw[n];
                vfk += gfw[k * 32 + n] * wfw[n];
            }
            u0 += w2jk * w0w[k];
            ub += w2jk * vbk;
            uf += w2jk * vfk;
        }
        par[96 + j]  = u0;
        par[128 + j] = ub;
        par[160 + j] = uf;
    }
    if (threadIdx.x == 0) {
        float C = w0b[0] + wbb[0] + wfb[0];
        float pc0 = 0.f, pcb = 0.f, pcf = 0.f;
        for (int k = 0; k < 32; k++) {
            float vbk = 0.f, vfk = 0.f;
            for (int n = 0; n < 32; n++) {
                vbk += gbw[k * 32 + n] * wbw[n];
                vfk += gfw[k * 32 + n] * wfw[n];
            }
            pc0 += b2[k] * w0w[k];
            pcb += b2[k] * vbk;
            pcf += b2[k] * vfk;
            C   += gbb[k] * wbw[k] + gfb[k] * wfw[k];
        }
        par[192] = C; par[193] = pc0; par[194] = pcb; par[195] = pcf;
    }
}

__global__ void k_nodes(const float* __restrict__ x, const float* __restrict__ prelu_a,
                        float* __restrict__ ws) {
    int i = blockIdx.x * blockDim.x + threadIdx.x;
    if (i >= N_NODES) return;
    const float* par = ws + WS_PAR;
    float alpha = prelu_a[0];
    float2 v = ((const float2*)x)[i];
    float p0 = par[193], pb = par[194], pf = par[195];
    #pragma unroll
    for (int j = 0; j < 32; j++) {
        float z = v.x * par[j] + v.y * par[32 + j] + par[64 + j];
        float h = z > 0.f ? z : alpha * z;
        p0 += h * par[96 + j];
        pb += h * par[128 + j];
        pf += h * par[160 + j];
    }
    ws[WS_P0 + i] = p0;
    ws[WS_PB + i] = pb;
    ws[WS_PF + i] = pf;
}

// one wave per edge; fused norm + dot; DVEC = D/4 (float4 per row)
template <int DVEC>
__global__ void k_edgesim(const float* __restrict__ feats, const int* __restrict__ ei,
                          float* __restrict__ sim, float* __restrict__ deg) {
    int wave = (int)((blockIdx.x * blockDim.x + threadIdx.x) >> 6);
    int lane = threadIdx.x & 63;
    if (wave >= N_EDGES) return;
    int s = ei[wave], d = ei[N_EDGES + wave];
    const float4* A = (const float4*)feats + (size_t)s * DVEC;
    const float4* B = (const float4*)feats + (size_t)d * DVEC;
    float ab = 0.f, aa = 0.f, bb = 0.f;
    #pragma unroll
    for (int k = 0; k < DVEC / 64; k++) {
        float4 a = A[lane + 64 * k];
        float4 b = B[lane + 64 * k];
        ab += a.x * b.x + a.y * b.y + a.z * b.z + a.w * b.w;
        aa += a.x * a.x + a.y * a.y + a.z * a.z + a.w * a.w;
        bb += b.x * b.x + b.y * b.y + b.z * b.z + b.w * b.w;
    }
    for (int off = 32; off; off >>= 1) {
        ab += __shfl_xor(ab, off);
        aa += __shfl_xor(aa, off);
        bb += __shfl_xor(bb, off);
    }
    if (lane == 0) {
        float sm = ab * rsqrtf(aa + 1e-12f) * rsqrtf(bb + 1e-12f);
        sm = fmaxf(sm, 0.f);
        sim[wave] = sm;
        if (sm > 0.f) atomicAdd(&deg[d], sm);
    }
}

__global__ void k_dn(float* __restrict__ ws) {
    int i = blockIdx.x * blockDim.x + threadIdx.x;
    if (i < 2 * N_NODES) {
        float* deg = ws + WS_DEGB;   // DEGB and DEGF are contiguous
        deg[i] = rsqrtf(fmaxf(deg[i], 1e-6f));
    }
}

__global__ void k_scatter(const int* __restrict__ ei, const float* __restrict__ sim,
                          const float* __restrict__ dn, const float* __restrict__ p,
                          float* __restrict__ acc) {
    int e = blockIdx.x * blockDim.x + threadIdx.x;
    if (e >= N_EDGES) return;
    float sm = sim[e];
    if (sm <= 0.f) return;
    int s = ei[e], d = ei[N_EDGES + e];
    float c = dn[s] * dn[d] * sm;
    atomicAdd(&acc[d], c * p[s]);
}

__global__ void k_final(float* __restrict__ out, const float* __restrict__ ws) {
    int i = blockIdx.x * blockDim.x + threadIdx.x;
    if (i >= N_NODES) return;
    float dnb = ws[WS_DEGB + i];
    float dnf = ws[WS_DEGF + i];
    out[i] = ws[WS_P0 + i]
           + dnb * dnb * ws[WS_PB + i]
           + dnf * dnf * ws[WS_PF + i]
           + ws[WS_ACC + i]
           + ws[WS_PAR + 192];
}

extern "C" void kernel_launch(void* const* d_in, const int* in_sizes, int n_in,
                              void* d_out, int out_size, void* d_ws, size_t ws_size,
                              hipStream_t stream) {
    const float* x     = (const float*)d_in[0];
    const float* bfeat = (const float*)d_in[1];
    const float* ffeat = (const float*)d_in[2];
    const int*   eib   = (const int*)d_in[3];
    const int*   eif   = (const int*)d_in[4];
    const float* w1    = (const float*)d_in[5];
    const float* b1    = (const float*)d_in[6];
    const float* gam   = (const float*)d_in[7];
    const float* bet   = (const float*)d_in[8];
    const float* pa    = (const float*)d_in[9];
    const float* w2    = (const float*)d_in[10];
    const float* b2    = (const float*)d_in[11];
    const float* w0w   = (const float*)d_in[12];
    const float* w0b   = (const float*)d_in[13];
    const float* gbw   = (const float*)d_in[14];
    const float* gbb   = (const float*)d_in[15];
    const float* gfw   = (const float*)d_in[16];
    const float* gfb   = (const float*)d_in[17];
    const float* wbw   = (const float*)d_in[18];
    const float* wbb   = (const float*)d_in[19];
    const float* wfw   = (const float*)d_in[20];
    const float* wfb   = (const float*)d_in[21];

    float* ws  = (float*)d_ws;
    float* out = (float*)d_out;

    k_init<<<dim3(64), dim3(256), 0, stream>>>(ws);
    k_stats<<<dim3(64), dim3(256), 0, stream>>>(x, ws);
    k_params<<<dim3(1), dim3(64), 0, stream>>>(w1, b1, gam, bet, w2, b2, w0w, w0b,
                                               gbw, gbb, gfw, gfb, wbw, wbb, wfw, wfb, ws);
    k_nodes<<<dim3(N_NODES / 256), dim3(256), 0, stream>>>(x, pa, ws);
    k_edgesim<DB / 4><<<dim3(N_EDGES / 4), dim3(256), 0, stream>>>(bfeat, eib,
                                                                   ws + WS_SIMB, ws + WS_DEGB);
    k_edgesim<DF / 4><<<dim3(N_EDGES / 4), dim3(256), 0, stream>>>(ffeat, eif,
                                                                   ws + WS_SIMF, ws + WS_DEGF);
    k_dn<<<dim3((2 * N_NODES + 255) / 256), dim3(256), 0, stream>>>(ws);
    k_scatter<<<dim3(N_EDGES / 256), dim3(256), 0, stream>>>(eib, ws + WS_SIMB,
                                                             ws + WS_DEGB, ws + WS_PB, ws + WS_ACC);
    k_scatter<<<dim3(N_EDGES / 256), dim3(256), 0, stream>>>(eif, ws + WS_SIMF,
                                                             ws + WS_DEGF, ws + WS_PF, ws + WS_ACC);
    k_final<<<dim3(N_NODES / 256), dim3(256), 0, stream>>>(out, ws);
}

// Round 2
// 314.936 us; speedup vs baseline: 1.3895x; 1.3895x over previous
//
#include <hip/hip_runtime.h>

#define N_NODES 16384
#define N_EDGES 131072
#define DB 2048
#define DF 512

// ---- workspace layout (float offsets) ----
#define WS_STATS 0                      // 8 floats (5 used)
#define WS_PAR   8                      // 256 floats
#define WS_P0    512
#define WS_PB    (WS_P0 + N_NODES)
#define WS_PF    (WS_PB + N_NODES)
#define WS_DEGB  (WS_PF + N_NODES)
#define WS_DEGF  (WS_DEGB + N_NODES)
#define WS_ACC   (WS_DEGF + N_NODES)
#define WS_SIMB  (WS_ACC + N_NODES)
#define WS_SIMF  (WS_SIMB + N_EDGES)
#define WS_BASE_END (WS_SIMF + N_EDGES)            // 360960 floats
// bf16 normalized features (optional, if ws_size permits)
#define WS_FNB   WS_BASE_END                       // N*DB bf16 = N*DB/2 floats
#define WS_FNF   (WS_FNB + N_NODES * DB / 2)       // N*DF bf16
#define WS_NEED_BYTES ((size_t)(WS_FNF + N_NODES * DF / 2) * 4)

__global__ void k_init(float* __restrict__ ws) {
    int i = blockIdx.x * blockDim.x + threadIdx.x;
    if (i < 8) ws[WS_STATS + i] = 0.f;
    if (i < N_NODES) {
        ws[WS_DEGB + i] = 1.f;   // self-loop weight
        ws[WS_DEGF + i] = 1.f;
        ws[WS_ACC  + i] = 0.f;
    }
}

__global__ void k_stats(const float* __restrict__ x, float* __restrict__ ws) {
    float s0 = 0.f, s1 = 0.f, s2 = 0.f, s3 = 0.f, s4 = 0.f;
    for (int i = blockIdx.x * blockDim.x + threadIdx.x; i < N_NODES;
         i += gridDim.x * blockDim.x) {
        float2 v = ((const float2*)x)[i];
        s0 += v.x; s1 += v.y;
        s2 += v.x * v.x; s3 += v.y * v.y; s4 += v.x * v.y;
    }
    for (int off = 32; off; off >>= 1) {
        s0 += __shfl_down(s0, off);
        s1 += __shfl_down(s1, off);
        s2 += __shfl_down(s2, off);
        s3 += __shfl_down(s3, off);
        s4 += __shfl_down(s4, off);
    }
    if ((threadIdx.x & 63) == 0) {
        atomicAdd(&ws[WS_STATS + 0], s0);
        atomicAdd(&ws[WS_STATS + 1], s1);
        atomicAdd(&ws[WS_STATS + 2], s2);
        atomicAdd(&ws[WS_STATS + 3], s3);
        atomicAdd(&ws[WS_STATS + 4], s4);
    }
}

__global__ void k_params(const float* __restrict__ w1, const float* __restrict__ b1,
                         const float* __restrict__ gamma, const float* __restrict__ beta,
                         const float* __restrict__ w2, const float* __restrict__ b2,
                         const float* __restrict__ w0w, const float* __restrict__ w0b,
                         const float* __restrict__ gbw, const float* __restrict__ gbb,
                         const float* __restrict__ gfw, const float* __restrict__ gfb,
                         const float* __restrict__ wbw, const float* __restrict__ wbb,
                         const float* __restrict__ wfw, const float* __restrict__ wfb,
                         float* __restrict__ ws) {
    const float inv_n = 1.0f / (float)N_NODES;
    float S0 = ws[WS_STATS+0], S1 = ws[WS_STATS+1], S2 = ws[WS_STATS+2],
          S3 = ws[WS_STATS+3], S4 = ws[WS_STATS+4];
    float m0 = S0 * inv_n, m1 = S1 * inv_n;
    float v0 = S2 * inv_n - m0 * m0;
    float v1 = S3 * inv_n - m1 * m1;
    float cv = S4 * inv_n - m0 * m1;
    float* par = ws + WS_PAR;
    int j = threadIdx.x;
    if (j < 32) {
        float W0 = w1[j], W1 = w1[32 + j];
        float mu  = m0 * W0 + m1 * W1 + b1[j];
        float var = W0 * W0 * v0 + W1 * W1 * v1 + 2.f * W0 * W1 * cv;
        float is  = rsqrtf(var + 1e-5f) * gamma[j];
        par[j]      = W0 * is;
        par[32 + j] = W1 * is;
        par[64 + j] = (b1[j] - mu) * is + beta[j];
        float u0 = 0.f, ub = 0.f, uf = 0.f;
        for (int k = 0; k < 32; k++) {
            float w2jk = w2[j * 32 + k];
            float vbk = 0.f, vfk = 0.f;
            for (int n = 0; n < 32; n++) {
                vbk += gbw[k * 32 + n] * wbw[n];
                vfk += gfw[k * 32 + n] * wfw[n];
            }
            u0 += w2jk * w0w[k];
            ub += w2jk * vbk;
            uf += w2jk * vfk;
        }
        par[96 + j]  = u0;
        par[128 + j] = ub;
        par[160 + j] = uf;
    }
    if (threadIdx.x == 0) {
        float C = w0b[0] + wbb[0] + wfb[0];
        float pc0 = 0.f, pcb = 0.f, pcf = 0.f;
        for (int k = 0; k < 32; k++) {
            float vbk = 0.f, vfk = 0.f;
            for (int n = 0; n < 32; n++) {
                vbk += gbw[k * 32 + n] * wbw[n];
                vfk += gfw[k * 32 + n] * wfw[n];
            }
            pc0 += b2[k] * w0w[k];
            pcb += b2[k] * vbk;
            pcf += b2[k] * vfk;
            C   += gbb[k] * wbw[k] + gfb[k] * wfw[k];
        }
        par[192] = C; par[193] = pc0; par[194] = pcb; par[195] = pcf;
    }
}

__global__ void k_nodes(const float* __restrict__ x, const float* __restrict__ prelu_a,
                        float* __restrict__ ws) {
    int i = blockIdx.x * blockDim.x + threadIdx.x;
    if (i >= N_NODES) return;
    const float* par = ws + WS_PAR;
    float alpha = prelu_a[0];
    float2 v = ((const float2*)x)[i];
    float p0 = par[193], pb = par[194], pf = par[195];
    #pragma unroll
    for (int j = 0; j < 32; j++) {
        float z = v.x * par[j] + v.y * par[32 + j] + par[64 + j];
        float h = z > 0.f ? z : alpha * z;
        p0 += h * par[96 + j];
        pb += h * par[128 + j];
        pf += h * par[160 + j];
    }
    ws[WS_P0 + i] = p0;
    ws[WS_PB + i] = pb;
    ws[WS_PF + i] = pf;
}

// ---- bf16 helpers ----
__device__ __forceinline__ uint32_t bf16_rn(float x) {
    uint32_t u = __float_as_uint(x);
    return (u + 0x7fffu + ((u >> 16) & 1u)) >> 16;
}
__device__ __forceinline__ uint32_t pack_bf16(float lo, float hi) {
    return bf16_rn(lo) | (bf16_rn(hi) << 16);
}
__device__ __forceinline__ float bl(uint32_t u) { return __uint_as_float(u << 16); }
__device__ __forceinline__ float bh(uint32_t u) { return __uint_as_float(u & 0xffff0000u); }
__device__ __forceinline__ float dot8(uint4 a, uint4 b) {
    float s = bl(a.x) * bl(b.x) + bh(a.x) * bh(b.x);
    s += bl(a.y) * bl(b.y) + bh(a.y) * bh(b.y);
    s += bl(a.z) * bl(b.z) + bh(a.z) * bh(b.z);
    s += bl(a.w) * bl(b.w) + bh(a.w) * bh(b.w);
    return s;
}

// one wave per node: L2-normalize row, emit bf16
template <int D>
__global__ void k_normalize(const float* __restrict__ feats, uint4* __restrict__ fn) {
    int wid  = (int)((blockIdx.x * blockDim.x + threadIdx.x) >> 6);
    int lane = threadIdx.x & 63;
    if (wid >= N_NODES) return;
    const float4* F = (const float4*)feats + (size_t)wid * (D / 4);
    float4 va[D / 512][2];
    float aa = 0.f;
    #pragma unroll
    for (int k = 0; k < D / 512; k++) {
        float4 a0 = F[2 * lane + 128 * k];
        float4 a1 = F[2 * lane + 128 * k + 1];
        va[k][0] = a0; va[k][1] = a1;
        aa += a0.x * a0.x + a0.y * a0.y + a0.z * a0.z + a0.w * a0.w;
        aa += a1.x * a1.x + a1.y * a1.y + a1.z * a1.z + a1.w * a1.w;
    }
    #pragma unroll
    for (int off = 32; off; off >>= 1) aa += __shfl_xor(aa, off);
    float inv = rsqrtf(aa + 1e-12f);
    uint4* O = fn + (size_t)wid * (D / 8);
    #pragma unroll
    for (int k = 0; k < D / 512; k++) {
        float4 a0 = va[k][0], a1 = va[k][1];
        uint4 o;
        o.x = pack_bf16(a0.x * inv, a0.y * inv);
        o.y = pack_bf16(a0.z * inv, a0.w * inv);
        o.z = pack_bf16(a1.x * inv, a1.y * inv);
        o.w = pack_bf16(a1.z * inv, a1.w * inv);
        O[lane + 64 * k] = o;
    }
}

// one wave per edge, pre-normalized bf16 rows: sim = relu(dot)
template <int D>
__global__ void k_edgesim_bf16(const uint4* __restrict__ fn, const int* __restrict__ ei,
                               float* __restrict__ sim, float* __restrict__ deg) {
    int wave = (int)((blockIdx.x * blockDim.x + threadIdx.x) >> 6);
    int lane = threadIdx.x & 63;
    if (wave >= N_EDGES) return;
    int s = ei[wave], d = ei[N_EDGES + wave];
    const uint4* A = fn + (size_t)s * (D / 8);
    const uint4* B = fn + (size_t)d * (D / 8);
    float ab = 0.f;
    #pragma unroll
    for (int k = 0; k < D / 512; k++) {
        uint4 a = A[lane + 64 * k];
        uint4 b = B[lane + 64 * k];
        ab += dot8(a, b);
    }
    #pragma unroll
    for (int off = 32; off; off >>= 1) ab += __shfl_xor(ab, off);
    if (lane == 0) {
        float sm = fmaxf(ab, 0.f);
        sim[wave] = sm;
        if (sm > 0.f) atomicAdd(&deg[d], sm);
    }
}

// fp32 fallback (used only if ws too small for bf16 buffers)
template <int DVEC>
__global__ void k_edgesim(const float* __restrict__ feats, const int* __restrict__ ei,
                          float* __restrict__ sim, float* __restrict__ deg) {
    int wave = (int)((blockIdx.x * blockDim.x + threadIdx.x) >> 6);
    int lane = threadIdx.x & 63;
    if (wave >= N_EDGES) return;
    int s = ei[wave], d = ei[N_EDGES + wave];
    const float4* A = (const float4*)feats + (size_t)s * DVEC;
    const float4* B = (const float4*)feats + (size_t)d * DVEC;
    float ab = 0.f, aa = 0.f, bb = 0.f;
    #pragma unroll
    for (int k = 0; k < DVEC / 64; k++) {
        float4 a = A[lane + 64 * k];
        float4 b = B[lane + 64 * k];
        ab += a.x * b.x + a.y * b.y + a.z * b.z + a.w * b.w;
        aa += a.x * a.x + a.y * a.y + a.z * a.z + a.w * a.w;
        bb += b.x * b.x + b.y * b.y + b.z * b.z + b.w * b.w;
    }
    for (int off = 32; off; off >>= 1) {
        ab += __shfl_xor(ab, off);
        aa += __shfl_xor(aa, off);
        bb += __shfl_xor(bb, off);
    }
    if (lane == 0) {
        float sm = ab * rsqrtf(aa + 1e-12f) * rsqrtf(bb + 1e-12f);
        sm = fmaxf(sm, 0.f);
        sim[wave] = sm;
        if (sm > 0.f) atomicAdd(&deg[d], sm);
    }
}

__global__ void k_dn(float* __restrict__ ws) {
    int i = blockIdx.x * blockDim.x + threadIdx.x;
    if (i < 2 * N_NODES) {
        float* deg = ws + WS_DEGB;   // DEGB and DEGF contiguous
        deg[i] = rsqrtf(fmaxf(deg[i], 1e-6f));
    }
}

__global__ void k_scatter(const int* __restrict__ ei, const float* __restrict__ sim,
                          const float* __restrict__ dn, const float* __restrict__ p,
                          float* __restrict__ acc) {
    int e = blockIdx.x * blockDim.x + threadIdx.x;
    if (e >= N_EDGES) return;
    float sm = sim[e];
    if (sm <= 0.f) return;
    int s = ei[e], d = ei[N_EDGES + e];
    float c = dn[s] * dn[d] * sm;
    atomicAdd(&acc[d], c * p[s]);
}

__global__ void k_final(float* __restrict__ out, const float* __restrict__ ws) {
    int i = blockIdx.x * blockDim.x + threadIdx.x;
    if (i >= N_NODES) return;
    float dnb = ws[WS_DEGB + i];
    float dnf = ws[WS_DEGF + i];
    out[i] = ws[WS_P0 + i]
           + dnb * dnb * ws[WS_PB + i]
           + dnf * dnf * ws[WS_PF + i]
           + ws[WS_ACC + i]
           + ws[WS_PAR + 192];
}

extern "C" void kernel_launch(void* const* d_in, const int* in_sizes, int n_in,
                              void* d_out, int out_size, void* d_ws, size_t ws_size,
                              hipStream_t stream) {
    const float* x     = (const float*)d_in[0];
    const float* bfeat = (const float*)d_in[1];
    const float* ffeat = (const float*)d_in[2];
    const int*   eib   = (const int*)d_in[3];
    const int*   eif   = (const int*)d_in[4];
    const float* w1    = (const float*)d_in[5];
    const float* b1    = (const float*)d_in[6];
    const float* gam   = (const float*)d_in[7];
    const float* bet   = (const float*)d_in[8];
    const float* pa    = (const float*)d_in[9];
    const float* w2    = (const float*)d_in[10];
    const float* b2    = (const float*)d_in[11];
    const float* w0w   = (const float*)d_in[12];
    const float* w0b   = (const float*)d_in[13];
    const float* gbw   = (const float*)d_in[14];
    const float* gbb   = (const float*)d_in[15];
    const float* gfw   = (const float*)d_in[16];
    const float* gfb   = (const float*)d_in[17];
    const float* wbw   = (const float*)d_in[18];
    const float* wbb   = (const float*)d_in[19];
    const float* wfw   = (const float*)d_in[20];
    const float* wfb   = (const float*)d_in[21];

    float* ws  = (float*)d_ws;
    float* out = (float*)d_out;

    k_init<<<dim3(64), dim3(256), 0, stream>>>(ws);
    k_stats<<<dim3(64), dim3(256), 0, stream>>>(x, ws);
    k_params<<<dim3(1), dim3(64), 0, stream>>>(w1, b1, gam, bet, w2, b2, w0w, w0b,
                                               gbw, gbb, gfw, gfb, wbw, wbb, wfw, wfb, ws);
    k_nodes<<<dim3(N_NODES / 256), dim3(256), 0, stream>>>(x, pa, ws);

    if (ws_size >= WS_NEED_BYTES) {
        uint4* fnb = (uint4*)(ws + WS_FNB);
        uint4* fnf = (uint4*)(ws + WS_FNF);
        k_normalize<DB><<<dim3(N_NODES / 4), dim3(256), 0, stream>>>(bfeat, fnb);
        k_normalize<DF><<<dim3(N_NODES / 4), dim3(256), 0, stream>>>(ffeat, fnf);
        k_edgesim_bf16<DB><<<dim3(N_EDGES / 4), dim3(256), 0, stream>>>(fnb, eib,
                                                                        ws + WS_SIMB, ws + WS_DEGB);
        k_edgesim_bf16<DF><<<dim3(N_EDGES / 4), dim3(256), 0, stream>>>(fnf, eif,
                                                                        ws + WS_SIMF, ws + WS_DEGF);
    } else {
        k_edgesim<DB / 4><<<dim3(N_EDGES / 4), dim3(256), 0, stream>>>(bfeat, eib,
                                                                       ws + WS_SIMB, ws + WS_DEGB);
        k_edgesim<DF / 4><<<dim3(N_EDGES / 4), dim3(256), 0, stream>>>(ffeat, eif,
                                                                       ws + WS_SIMF, ws + WS_DEGF);
    }

    k_dn<<<dim3((2 * N_NODES + 255) / 256), dim3(256), 0, stream>>>(ws);
    k_scatter<<<dim3(N_EDGES / 256), dim3(256), 0, stream>>>(eib, ws + WS_SIMB,
                                                             ws + WS_DEGB, ws + WS_PB, ws + WS_ACC);
    k_scatter<<<dim3(N_EDGES / 256), dim3(256), 0, stream>>>(eif, ws + WS_SIMF,
                                                             ws + WS_DEGF, ws + WS_PF, ws + WS_ACC);
    k_final<<<dim3(N_NODES / 256), dim3(256), 0, stream>>>(out, ws);
}

// Round 3
// 293.444 us; speedup vs baseline: 1.4913x; 1.0732x over previous
//
#include <hip/hip_runtime.h>
#include <hip/hip_fp16.h>

#define N_NODES 16384
#define N_EDGES 131072
#define DB 2048
#define DF 512

// ---- workspace layout (float-unit offsets), total 85,328,960 B ----
#define WS_STATS   0                               // 8
#define WS_PAR     8                               // 256
#define WS_PBF     264                             // N packed (pb,pf) fp16 — aliased as CURF (int) during sort
#define WS_DEGB    (WS_PBF + N_NODES)
#define WS_DEGF    (WS_DEGB + N_NODES)
#define WS_ACC     (WS_DEGF + N_NODES)             // aliased as CURB (int) during sort; later p0+C+scatter
#define WS_STARTB  (WS_ACC + N_NODES)              // N+4 ints (exclusive prefix, [N]=E)
#define WS_STARTF  (WS_STARTB + N_NODES + 4)
#define WS_EDGEB   (WS_STARTF + N_NODES + 4)       // E words: dst | (sim_fp16 << 16)
#define WS_EDGEF   (WS_EDGEB + N_EDGES)
#define WS_FNB     (WS_EDGEF + N_EDGES)            // N*DB fp16
#define WS_FNF     (WS_FNB + N_NODES * DB / 2)     // N*DF fp16
#define WS_END     (WS_FNF + N_NODES * DF / 2)

// ---- fp16 helpers ----
__device__ __forceinline__ uint32_t pack_h2(float x, float y) {
    union { __half2 h; uint32_t u; } c; c.h = __floats2half2_rn(x, y); return c.u;
}
__device__ __forceinline__ uint16_t f2h_bits(float f) {
    union { __half h; uint16_t u; } c; c.h = __float2half_rn(f); return c.u;
}
__device__ __forceinline__ float h_bits2f(uint16_t u) {
    union { uint16_t u; __half h; } c; c.u = u; return __half2float(c.h);
}

typedef _Float16 hv2 __attribute__((ext_vector_type(2)));
__device__ __forceinline__ float d2(uint32_t a, uint32_t b, float acc) {
#if __has_builtin(__builtin_amdgcn_fdot2)
    union { uint32_t u; hv2 h; } ca, cb; ca.u = a; cb.u = b;
    return __builtin_amdgcn_fdot2(ca.h, cb.h, acc, false);
#else
    union { uint32_t u; __half2 h; } ca, cb; ca.u = a; cb.u = b;
    float2 fa = __half22float2(ca.h), fb = __half22float2(cb.h);
    return acc + fa.x * fb.x + fa.y * fb.y;
#endif
}
__device__ __forceinline__ float dot8h(uint4 a, uint4 b, float acc) {
    acc = d2(a.x, b.x, acc); acc = d2(a.y, b.y, acc);
    acc = d2(a.z, b.z, acc); acc = d2(a.w, b.w, acc);
    return acc;
}

__global__ void k_init(float* __restrict__ ws) {
    int i = blockIdx.x * blockDim.x + threadIdx.x;
    if (i < 8) ws[WS_STATS + i] = 0.f;
    if (i < N_NODES) { ws[WS_DEGB + i] = 1.f; ws[WS_DEGF + i] = 1.f; }
    int* sb = (int*)(ws + WS_STARTB);
    int* sf = (int*)(ws + WS_STARTF);
    if (i < N_NODES + 4) { sb[i] = 0; sf[i] = 0; }
}

__global__ void k_stats(const float* __restrict__ x, float* __restrict__ ws) {
    float s0 = 0.f, s1 = 0.f, s2 = 0.f, s3 = 0.f, s4 = 0.f;
    for (int i = blockIdx.x * blockDim.x + threadIdx.x; i < N_NODES;
         i += gridDim.x * blockDim.x) {
        float2 v = ((const float2*)x)[i];
        s0 += v.x; s1 += v.y;
        s2 += v.x * v.x; s3 += v.y * v.y; s4 += v.x * v.y;
    }
    for (int off = 32; off; off >>= 1) {
        s0 += __shfl_down(s0, off);
        s1 += __shfl_down(s1, off);
        s2 += __shfl_down(s2, off);
        s3 += __shfl_down(s3, off);
        s4 += __shfl_down(s4, off);
    }
    if ((threadIdx.x & 63) == 0) {
        atomicAdd(&ws[WS_STATS + 0], s0);
        atomicAdd(&ws[WS_STATS + 1], s1);
        atomicAdd(&ws[WS_STATS + 2], s2);
        atomicAdd(&ws[WS_STATS + 3], s3);
        atomicAdd(&ws[WS_STATS + 4], s4);
    }
}

__global__ void k_params(const float* __restrict__ w1, const float* __restrict__ b1,
                         const float* __restrict__ gamma, const float* __restrict__ beta,
                         const float* __restrict__ w2, const float* __restrict__ b2,
                         const float* __restrict__ w0w, const float* __restrict__ w0b,
                         const float* __restrict__ gbw, const float* __restrict__ gbb,
                         const float* __restrict__ gfw, const float* __restrict__ gfb,
                         const float* __restrict__ wbw, const float* __restrict__ wbb,
                         const float* __restrict__ wfw, const float* __restrict__ wfb,
                         float* __restrict__ ws) {
    const float inv_n = 1.0f / (float)N_NODES;
    float S0 = ws[WS_STATS+0], S1 = ws[WS_STATS+1], S2 = ws[WS_STATS+2],
          S3 = ws[WS_STATS+3], S4 = ws[WS_STATS+4];
    float m0 = S0 * inv_n, m1 = S1 * inv_n;
    float v0 = S2 * inv_n - m0 * m0;
    float v1 = S3 * inv_n - m1 * m1;
    float cv = S4 * inv_n - m0 * m1;
    float* par = ws + WS_PAR;
    int j = threadIdx.x;
    if (j < 32) {
        float W0 = w1[j], W1 = w1[32 + j];
        float mu  = m0 * W0 + m1 * W1 + b1[j];
        float var = W0 * W0 * v0 + W1 * W1 * v1 + 2.f * W0 * W1 * cv;
        float is  = rsqrtf(var + 1e-5f) * gamma[j];
        par[j]      = W0 * is;
        par[32 + j] = W1 * is;
        par[64 + j] = (b1[j] - mu) * is + beta[j];
        float u0 = 0.f, ub = 0.f, uf = 0.f;
        for (int k = 0; k < 32; k++) {
            float w2jk = w2[j * 32 + k];
            float vbk = 0.f, vfk = 0.f;
            for (int n = 0; n < 32; n++) {
                vbk += gbw[k * 32 + n] * wbw[n];
                vfk += gfw[k * 32 + n] * wfw[n];
            }
            u0 += w2jk * w0w[k];
            ub += w2jk * vbk;
            uf += w2jk * vfk;
        }
        par[96 + j]  = u0;
        par[128 + j] = ub;
        par[160 + j] = uf;
    }
    if (threadIdx.x == 0) {
        float C = w0b[0] + wbb[0] + wfb[0];
        float pc0 = 0.f, pcb = 0.f, pcf = 0.f;
        for (int k = 0; k < 32; k++) {
            float vbk = 0.f, vfk = 0.f;
            for (int n = 0; n < 32; n++) {
                vbk += gbw[k * 32 + n] * wbw[n];
                vfk += gfw[k * 32 + n] * wfw[n];
            }
            pc0 += b2[k] * w0w[k];
            pcb += b2[k] * vbk;
            pcf += b2[k] * vfk;
            C   += gbb[k] * wbw[k] + gfb[k] * wfw[k];
        }
        par[192] = C; par[193] = pc0; par[194] = pcb; par[195] = pcf;
    }
}

// counting-sort step 1: out-degree histogram (into START arrays, zeroed by k_init)
__global__ void k_hist(const int* __restrict__ eib, const int* __restrict__ eif,
                       float* __restrict__ ws) {
    int e = blockIdx.x * blockDim.x + threadIdx.x;
    int* sb = (int*)(ws + WS_STARTB);
    int* sf = (int*)(ws + WS_STARTF);
    if (e < N_EDGES) {
        atomicAdd(&sb[eib[e]], 1);
    } else {
        int e2 = e - N_EDGES;
        if (e2 < N_EDGES) atomicAdd(&sf[eif[e2]], 1);
    }
}

// step 2: exclusive prefix (in place) + cursor init. single block, 256 threads.
__global__ void k_scan(float* __restrict__ ws) {
    __shared__ int part[256];
    int t = threadIdx.x;
    for (int g = 0; g < 2; g++) {
        int* st = (int*)(ws + (g ? WS_STARTF : WS_STARTB));
        int* cu = (int*)(ws + (g ? WS_PBF : WS_ACC));     // cursors alias dead float regions
        int base = t * 64;
        int s = 0;
        for (int j = 0; j < 64; j++) s += st[base + j];
        part[t] = s;
        __syncthreads();
        if (t == 0) {
            int run = 0;
            for (int k = 0; k < 256; k++) { int v = part[k]; part[k] = run; run += v; }
        }
        __syncthreads();
        int off = part[t];
        for (int j = 0; j < 64; j++) {
            int c = st[base + j];
            st[base + j] = off; cu[base + j] = off; off += c;
        }
        if (t == 255) st[N_NODES] = off;
        __syncthreads();
    }
}

// step 3: scatter dst into src-sorted buckets
__global__ void k_sortscatter(const int* __restrict__ eib, const int* __restrict__ eif,
                              float* __restrict__ ws) {
    int e = blockIdx.x * blockDim.x + threadIdx.x;
    if (e < N_EDGES) {
        int s = eib[e], d = eib[N_EDGES + e];
        int* cur = (int*)(ws + WS_ACC);
        uint32_t* eb = (uint32_t*)(ws + WS_EDGEB);
        int pos = atomicAdd(&cur[s], 1);
        eb[pos] = (uint32_t)d;
    } else {
        int e2 = e - N_EDGES;
        if (e2 < N_EDGES) {
            int s = eif[e2], d = eif[N_EDGES + e2];
            int* cur = (int*)(ws + WS_PBF);
            uint32_t* ef = (uint32_t*)(ws + WS_EDGEF);
            int pos = atomicAdd(&cur[s], 1);
            ef[pos] = (uint32_t)d;
        }
    }
}

// per-node scalars: ACC = p0 + C; PBF = packed(pb,pf). MUST run after k_sortscatter.
__global__ void k_nodes(const float* __restrict__ x, const float* __restrict__ prelu_a,
                        float* __restrict__ ws) {
    int i = blockIdx.x * blockDim.x + threadIdx.x;
    if (i >= N_NODES) return;
    const float* par = ws + WS_PAR;
    float alpha = prelu_a[0];
    float2 v = ((const float2*)x)[i];
    float p0 = par[193], pb = par[194], pf = par[195];
    #pragma unroll
    for (int j = 0; j < 32; j++) {
        float z = v.x * par[j] + v.y * par[32 + j] + par[64 + j];
        float h = z > 0.f ? z : alpha * z;
        p0 += h * par[96 + j];
        pb += h * par[128 + j];
        pf += h * par[160 + j];
    }
    ws[WS_ACC + i] = p0 + par[192];
    ((uint32_t*)(ws + WS_PBF))[i] = pack_h2(pb, pf);
}

// one wave per node: L2-normalize row, emit fp16
template <int D>
__global__ void k_normalize(const float* __restrict__ feats, uint4* __restrict__ fn) {
    int wid  = (int)((blockIdx.x * blockDim.x + threadIdx.x) >> 6);
    int lane = threadIdx.x & 63;
    if (wid >= N_NODES) return;
    constexpr int L = D / 512;
    const float4* F = (const float4*)feats + (size_t)wid * (D / 4);
    float4 va[L][2];
    float aa = 0.f;
    #pragma unroll
    for (int k = 0; k < L; k++) {
        float4 a0 = F[2 * lane + 128 * k];
        float4 a1 = F[2 * lane + 128 * k + 1];
        va[k][0] = a0; va[k][1] = a1;
        aa += a0.x * a0.x + a0.y * a0.y + a0.z * a0.z + a0.w * a0.w;
        aa += a1.x * a1.x + a1.y * a1.y + a1.z * a1.z + a1.w * a1.w;
    }
    #pragma unroll
    for (int off = 32; off; off >>= 1) aa += __shfl_xor(aa, off);
    float inv = rsqrtf(aa + 1e-12f);
    uint4* O = fn + (size_t)wid * (64 * L);
    #pragma unroll
    for (int k = 0; k < L; k++) {
        float4 a0 = va[k][0], a1 = va[k][1];
        uint4 o;
        o.x = pack_h2(a0.x * inv, a0.y * inv);
        o.y = pack_h2(a0.z * inv, a0.w * inv);
        o.z = pack_h2(a1.x * inv, a1.y * inv);
        o.w = pack_h2(a1.z * inv, a1.w * inv);
        O[lane + 64 * k] = o;
    }
}

// one wave per SRC node: src row in registers, gather dst rows (2-edge unroll).
// writes sim (fp16) into edge word high bits; accumulates weighted in-degree.
template <int D>
__global__ void k_edge_grouped(float* __restrict__ ws, const uint4* __restrict__ fn,
                               const int* __restrict__ start, uint32_t* __restrict__ edges,
                               float* __restrict__ deg) {
    constexpr int L = D / 512;                 // uint4 per lane per row; row stride = 64*L uint4
    int wid  = (int)((blockIdx.x * blockDim.x + threadIdx.x) >> 6);
    int lane = threadIdx.x & 63;
    if (wid >= N_NODES) return;
    int st = start[wid], en = start[wid + 1];
    if (st >= en) return;
    const uint4* S = fn + (size_t)wid * (64 * L);
    uint4 srow[L];
    #pragma unroll
    for (int k = 0; k < L; k++) srow[k] = S[lane + 64 * k];
    int i = st;
    for (; i + 1 < en; i += 2) {
        int dA = (int)(edges[i] & 0xFFFFu), dB = (int)(edges[i + 1] & 0xFFFFu);
        const uint4* A = fn + (size_t)dA * (64 * L);
        const uint4* B = fn + (size_t)dB * (64 * L);
        uint4 ra[L], rb[L];
        #pragma unroll
        for (int k = 0; k < L; k++) ra[k] = A[lane + 64 * k];
        #pragma unroll
        for (int k = 0; k < L; k++) rb[k] = B[lane + 64 * k];
        float da = 0.f, db = 0.f;
        #pragma unroll
        for (int k = 0; k < L; k++) { da = dot8h(srow[k], ra[k], da); db = dot8h(srow[k], rb[k], db); }
        #pragma unroll
        for (int off = 32; off; off >>= 1) { da += __shfl_xor(da, off); db += __shfl_xor(db, off); }
        if (lane == 0) {
            float sA = fmaxf(da, 0.f), sB = fmaxf(db, 0.f);
            edges[i]     = (uint32_t)dA | ((uint32_t)f2h_bits(sA) << 16);
            edges[i + 1] = (uint32_t)dB | ((uint32_t)f2h_bits(sB) << 16);
            if (sA > 0.f) atomicAdd(&deg[dA], sA);
            if (sB > 0.f) atomicAdd(&deg[dB], sB);
        }
    }
    if (i < en) {
        int dA = (int)(edges[i] & 0xFFFFu);
        const uint4* A = fn + (size_t)dA * (64 * L);
        uint4 ra[L];
        #pragma unroll
        for (int k = 0; k < L; k++) ra[k] = A[lane + 64 * k];
        float da = 0.f;
        #pragma unroll
        for (int k = 0; k < L; k++) da = dot8h(srow[k], ra[k], da);
        #pragma unroll
        for (int off = 32; off; off >>= 1) da += __shfl_xor(da, off);
        if (lane == 0) {
            float sA = fmaxf(da, 0.f);
            edges[i] = (uint32_t)dA | ((uint32_t)f2h_bits(sA) << 16);
            if (sA > 0.f) atomicAdd(&deg[dA], sA);
        }
    }
}

__global__ void k_dn(float* __restrict__ ws) {
    int i = blockIdx.x * blockDim.x + threadIdx.x;
    if (i < 2 * N_NODES) {
        float* deg = ws + WS_DEGB;   // DEGB and DEGF contiguous
        deg[i] = rsqrtf(fmaxf(deg[i], 1e-6f));
    }
}

// one thread per (graph, src): scatter dn[s]*dn[d]*sim*p[s] into acc[d]
__global__ void k_scatter_grouped(float* __restrict__ ws) {
    int t = blockIdx.x * blockDim.x + threadIdx.x;
    if (t >= 2 * N_NODES) return;
    int s = t & (N_NODES - 1);
    int g = t >> 14;
    const int* start = (const int*)(ws + (g ? WS_STARTF : WS_STARTB));
    int st = start[s], en = start[s + 1];
    if (st >= en) return;
    const uint32_t* edges = (const uint32_t*)(ws + (g ? WS_EDGEF : WS_EDGEB));
    const float* dn = ws + (g ? WS_DEGF : WS_DEGB);
    uint32_t pk = ((const uint32_t*)(ws + WS_PBF))[s];
    float p = h_bits2f(g ? (uint16_t)(pk >> 16) : (uint16_t)(pk & 0xFFFFu));
    float c0 = dn[s] * p;
    float* acc = ws + WS_ACC;
    for (int e = st; e < en; e++) {
        uint32_t w = edges[e];
        float sm = h_bits2f((uint16_t)(w >> 16));
        if (sm > 0.f) {
            int d = (int)(w & 0xFFFFu);
            atomicAdd(&acc[d], c0 * dn[d] * sm);
        }
    }
}

__global__ void k_final(float* __restrict__ out, const float* __restrict__ ws) {
    int i = blockIdx.x * blockDim.x + threadIdx.x;
    if (i >= N_NODES) return;
    float dnb = ws[WS_DEGB + i];
    float dnf = ws[WS_DEGF + i];
    uint32_t pk = ((const uint32_t*)(ws + WS_PBF))[i];
    float pb = h_bits2f((uint16_t)(pk & 0xFFFFu));
    float pf = h_bits2f((uint16_t)(pk >> 16));
    out[i] = ws[WS_ACC + i] + dnb * dnb * pb + dnf * dnf * pf;
}

extern "C" void kernel_launch(void* const* d_in, const int* in_sizes, int n_in,
                              void* d_out, int out_size, void* d_ws, size_t ws_size,
                              hipStream_t stream) {
    const float* x     = (const float*)d_in[0];
    const float* bfeat = (const float*)d_in[1];
    const float* ffeat = (const float*)d_in[2];
    const int*   eib   = (const int*)d_in[3];
    const int*   eif   = (const int*)d_in[4];
    const float* w1    = (const float*)d_in[5];
    const float* b1    = (const float*)d_in[6];
    const float* gam   = (const float*)d_in[7];
    const float* bet   = (const float*)d_in[8];
    const float* pa    = (const float*)d_in[9];
    const float* w2    = (const float*)d_in[10];
    const float* b2    = (const float*)d_in[11];
    const float* w0w   = (const float*)d_in[12];
    const float* w0b   = (const float*)d_in[13];
    const float* gbw   = (const float*)d_in[14];
    const float* gbb   = (const float*)d_in[15];
    const float* gfw   = (const float*)d_in[16];
    const float* gfb   = (const float*)d_in[17];
    const float* wbw   = (const float*)d_in[18];
    const float* wbb   = (const float*)d_in[19];
    const float* wfw   = (const float*)d_in[20];
    const float* wfb   = (const float*)d_in[21];

    float* ws  = (float*)d_ws;
    float* out = (float*)d_out;
    uint4* fnb = (uint4*)(ws + WS_FNB);
    uint4* fnf = (uint4*)(ws + WS_FNF);

    k_init<<<dim3(65), dim3(256), 0, stream>>>(ws);
    k_stats<<<dim3(64), dim3(256), 0, stream>>>(x, ws);
    k_params<<<dim3(1), dim3(64), 0, stream>>>(w1, b1, gam, bet, w2, b2, w0w, w0b,
                                               gbw, gbb, gfw, gfb, wbw, wbb, wfw, wfb, ws);
    k_hist<<<dim3(1024), dim3(256), 0, stream>>>(eib, eif, ws);
    k_scan<<<dim3(1), dim3(256), 0, stream>>>(ws);
    k_sortscatter<<<dim3(1024), dim3(256), 0, stream>>>(eib, eif, ws);
    k_nodes<<<dim3(N_NODES / 256), dim3(256), 0, stream>>>(x, pa, ws);
    k_normalize<DB><<<dim3(N_NODES / 4), dim3(256), 0, stream>>>(bfeat, fnb);
    k_normalize<DF><<<dim3(N_NODES / 4), dim3(256), 0, stream>>>(ffeat, fnf);
    k_edge_grouped<DB><<<dim3(N_NODES / 4), dim3(256), 0, stream>>>(
        ws, fnb, (const int*)(ws + WS_STARTB), (uint32_t*)(ws + WS_EDGEB), ws + WS_DEGB);
    k_edge_grouped<DF><<<dim3(N_NODES / 4), dim3(256), 0, stream>>>(
        ws, fnf, (const int*)(ws + WS_STARTF), (uint32_t*)(ws + WS_EDGEF), ws + WS_DEGF);
    k_dn<<<dim3(128), dim3(256), 0, stream>>>(ws);
    k_scatter_grouped<<<dim3(128), dim3(256), 0, stream>>>(ws);
    k_final<<<dim3(N_NODES / 256), dim3(256), 0, stream>>>(out, ws);
}

// Round 4
// 197.275 us; speedup vs baseline: 2.2182x; 1.4875x over previous
//
#include <hip/hip_runtime.h>
#include <hip/hip_fp16.h>

#define N_NODES 16384
#define N_EDGES 131072
#define DB 2048
#define DF 512
#define FP8_SCALE 16.0f
#define FP8_DESCALE (1.0f / 256.0f)

// ---- workspace layout (float-unit offsets) ----
#define WS_STATS   0                               // 64 blocks x 5 partials = 320
#define WS_PAR     320                             // 256
#define WS_PBF     576                             // N packed (pb,pf) fp16 — aliased as CURF during sort
#define WS_DEGB    (WS_PBF + N_NODES)
#define WS_DEGF    (WS_DEGB + N_NODES)
#define WS_ACC     (WS_DEGF + N_NODES)             // aliased as CURB during sort; later p0+C+scatter
#define WS_STARTB  (WS_ACC + N_NODES)              // N+4 ints (exclusive prefix, [N]=E)
#define WS_STARTF  (WS_STARTB + N_NODES + 4)
#define WS_EDGEB   (WS_STARTF + N_NODES + 4)       // E words: dst | (sim_fp16 << 16)
#define WS_EDGEF   (WS_EDGEB + N_EDGES)
#define WS_FNB     (WS_EDGEF + N_EDGES)            // N*DB fp8 bytes = N*DB/4 floats
#define WS_FNF     (WS_FNB + N_NODES * DB / 4)     // N*DF fp8
#define WS_END     (WS_FNF + N_NODES * DF / 4)     // ~43.4 MB

typedef float fv2 __attribute__((ext_vector_type(2)));

#if __has_builtin(__builtin_amdgcn_cvt_pk_f32_fp8) && __has_builtin(__builtin_amdgcn_cvt_pk_fp8_f32)
#define HAS_FP8HW 1
#else
#define HAS_FP8HW 0
#endif

// ---- fp16 helpers ----
__device__ __forceinline__ uint32_t pack_h2(float x, float y) {
    union { __half2 h; uint32_t u; } c; c.h = __floats2half2_rn(x, y); return c.u;
}
__device__ __forceinline__ uint16_t f2h_bits(float f) {
    union { __half h; uint16_t u; } c; c.h = __float2half_rn(f); return c.u;
}
__device__ __forceinline__ float h_bits2f(uint16_t u) {
    union { uint16_t u; __half h; } c; c.u = u; return __half2float(c.h);
}

// ---- fp8 e4m3 helpers (HW path + soft fallback) ----
#if !HAS_FP8HW
__device__ __forceinline__ float fp8d_soft(uint32_t b) {
    uint32_t s = (b >> 7) & 1u, e = (b >> 3) & 0xFu, m = b & 7u;
    float v = (e == 0) ? (float)m * 0.001953125f
                       : (1.0f + (float)m * 0.125f) * exp2f((float)((int)e - 7));
    return s ? -v : v;
}
__device__ __forceinline__ uint32_t fp8e_soft(float f) {
    uint32_t s = (__float_as_uint(f) >> 31) << 7;
    float a = fabsf(f);
    if (a < 0.015625f) {            // subnormal
        int m = (int)rintf(a * 512.0f);
        if (m > 7) return s | (1u << 3);
        return s | (uint32_t)m;
    }
    uint32_t u = __float_as_uint(a);
    uint32_t r = u + 0x000FFFFFu + ((u >> 20) & 1u);   // RNE on 20 dropped bits
    int e8 = (int)(r >> 23) - 127 + 7;
    if (e8 >= 16) return s | (15u << 3) | 6u;           // clamp to 448
    return s | ((uint32_t)e8 << 3) | ((r >> 20) & 7u);
}
#endif

// decode 4 fp8 from u32, fma with 4 src floats
__device__ __forceinline__ float u32dot(uint32_t u, const float* s, float acc) {
#if HAS_FP8HW
    fv2 lo = __builtin_amdgcn_cvt_pk_f32_fp8(u, false);
    fv2 hi = __builtin_amdgcn_cvt_pk_f32_fp8(u, true);
    acc += s[0] * lo.x; acc += s[1] * lo.y;
    acc += s[2] * hi.x; acc += s[3] * hi.y;
#else
    acc += s[0] * fp8d_soft(u & 0xFF);
    acc += s[1] * fp8d_soft((u >> 8) & 0xFF);
    acc += s[2] * fp8d_soft((u >> 16) & 0xFF);
    acc += s[3] * fp8d_soft((u >> 24) & 0xFF);
#endif
    return acc;
}
__device__ __forceinline__ void u32cvt(uint32_t u, float* d) {
#if HAS_FP8HW
    fv2 lo = __builtin_amdgcn_cvt_pk_f32_fp8(u, false);
    fv2 hi = __builtin_amdgcn_cvt_pk_f32_fp8(u, true);
    d[0] = lo.x; d[1] = lo.y; d[2] = hi.x; d[3] = hi.y;
#else
    d[0] = fp8d_soft(u & 0xFF); d[1] = fp8d_soft((u >> 8) & 0xFF);
    d[2] = fp8d_soft((u >> 16) & 0xFF); d[3] = fp8d_soft((u >> 24) & 0xFF);
#endif
}
__device__ __forceinline__ uint32_t pack4_fp8(float a, float b, float c, float d) {
#if HAS_FP8HW
    uint32_t u = 0;
    u = __builtin_amdgcn_cvt_pk_fp8_f32(a, b, u, false);
    u = __builtin_amdgcn_cvt_pk_fp8_f32(c, d, u, true);
    return u;
#else
    return fp8e_soft(a) | (fp8e_soft(b) << 8) | (fp8e_soft(c) << 16) | (fp8e_soft(d) << 24);
#endif
}
__device__ __forceinline__ float dot16_fp8(uint4 r, const float* s, float acc) {
    acc = u32dot(r.x, s + 0, acc);  acc = u32dot(r.y, s + 4, acc);
    acc = u32dot(r.z, s + 8, acc);  acc = u32dot(r.w, s + 12, acc);
    return acc;
}

// ---- fused stats (blocks 0..63, per-block partials) + init (blocks 64..191) ----
__global__ void k_pre(const float* __restrict__ x, float* __restrict__ ws) {
    if (blockIdx.x < 64) {
        float s0 = 0.f, s1 = 0.f, s2 = 0.f, s3 = 0.f, s4 = 0.f;
        for (int i = blockIdx.x * 256 + threadIdx.x; i < N_NODES; i += 64 * 256) {
            float2 v = ((const float2*)x)[i];
            s0 += v.x; s1 += v.y;
            s2 += v.x * v.x; s3 += v.y * v.y; s4 += v.x * v.y;
        }
        #pragma unroll
        for (int off = 32; off; off >>= 1) {
            s0 += __shfl_down(s0, off); s1 += __shfl_down(s1, off);
            s2 += __shfl_down(s2, off); s3 += __shfl_down(s3, off);
            s4 += __shfl_down(s4, off);
        }
        __shared__ float red[4][5];
        int w = threadIdx.x >> 6;
        if ((threadIdx.x & 63) == 0) {
            red[w][0] = s0; red[w][1] = s1; red[w][2] = s2; red[w][3] = s3; red[w][4] = s4;
        }
        __syncthreads();
        if (threadIdx.x < 5) {
            float t = red[0][threadIdx.x] + red[1][threadIdx.x] +
                      red[2][threadIdx.x] + red[3][threadIdx.x];
            ws[WS_STATS + blockIdx.x * 5 + threadIdx.x] = t;
        }
    } else {
        int j = (blockIdx.x - 64) * 256 + threadIdx.x;   // j < 32768
        int* sb = (int*)(ws + WS_STARTB);
        int* sf = (int*)(ws + WS_STARTF);
        if (j < N_NODES + 4) { sb[j] = 0; sf[j] = 0; }
        ws[WS_DEGB + j] = 1.f;     // covers DEGB then DEGF (contiguous 2N)
    }
}

// counting-sort step 1: out-degree histogram
__global__ void k_hist(const int* __restrict__ eib, const int* __restrict__ eif,
                       float* __restrict__ ws) {
    int e = blockIdx.x * blockDim.x + threadIdx.x;
    int* sb = (int*)(ws + WS_STARTB);
    int* sf = (int*)(ws + WS_STARTF);
    if (e < N_EDGES) {
        atomicAdd(&sb[eib[e]], 1);
    } else {
        int e2 = e - N_EDGES;
        if (e2 < N_EDGES) atomicAdd(&sf[eif[e2]], 1);
    }
}

// block 0: derive closed-form params; block 1: prefix-scan both graphs
__global__ void k_small(const float* __restrict__ w1, const float* __restrict__ b1,
                        const float* __restrict__ gamma, const float* __restrict__ beta,
                        const float* __restrict__ w2, const float* __restrict__ b2,
                        const float* __restrict__ w0w, const float* __restrict__ w0b,
                        const float* __restrict__ gbw, const float* __restrict__ gbb,
                        const float* __restrict__ gfw, const float* __restrict__ gfb,
                        const float* __restrict__ wbw, const float* __restrict__ wbb,
                        const float* __restrict__ wfw, const float* __restrict__ wfb,
                        float* __restrict__ ws) {
    if (blockIdx.x == 0) {
        __shared__ float st[5];
        if (threadIdx.x < 5) {
            float t = 0.f;
            for (int b = 0; b < 64; b++) t += ws[WS_STATS + b * 5 + threadIdx.x];
            st[threadIdx.x] = t;
        }
        __syncthreads();
        const float inv_n = 1.0f / (float)N_NODES;
        float m0 = st[0] * inv_n, m1 = st[1] * inv_n;
        float v0 = st[2] * inv_n - m0 * m0;
        float v1 = st[3] * inv_n - m1 * m1;
        float cv = st[4] * inv_n - m0 * m1;
        float* par = ws + WS_PAR;
        int j = threadIdx.x;
        if (j < 32) {
            float W0 = w1[j], W1 = w1[32 + j];
            float mu  = m0 * W0 + m1 * W1 + b1[j];
            float var = W0 * W0 * v0 + W1 * W1 * v1 + 2.f * W0 * W1 * cv;
            float is  = rsqrtf(var + 1e-5f) * gamma[j];
            par[j]      = W0 * is;
            par[32 + j] = W1 * is;
            par[64 + j] = (b1[j] - mu) * is + beta[j];
            float u0 = 0.f, ub = 0.f, uf = 0.f;
            for (int k = 0; k < 32; k++) {
                float w2jk = w2[j * 32 + k];
                float vbk = 0.f, vfk = 0.f;
                for (int n = 0; n < 32; n++) {
                    vbk += gbw[k * 32 + n] * wbw[n];
                    vfk += gfw[k * 32 + n] * wfw[n];
                }
                u0 += w2jk * w0w[k];
                ub += w2jk * vbk;
                uf += w2jk * vfk;
            }
            par[96 + j]  = u0;
            par[128 + j] = ub;
            par[160 + j] = uf;
        }
        if (threadIdx.x == 0) {
            float C = w0b[0] + wbb[0] + wfb[0];
            float pc0 = 0.f, pcb = 0.f, pcf = 0.f;
            for (int k = 0; k < 32; k++) {
                float vbk = 0.f, vfk = 0.f;
                for (int n = 0; n < 32; n++) {
                    vbk += gbw[k * 32 + n] * wbw[n];
                    vfk += gfw[k * 32 + n] * wfw[n];
                }
                pc0 += b2[k] * w0w[k];
                pcb += b2[k] * vbk;
                pcf += b2[k] * vfk;
                C   += gbb[k] * wbw[k] + gfb[k] * wfw[k];
            }
            par[192] = C; par[193] = pc0; par[194] = pcb; par[195] = pcf;
        }
    } else {
        __shared__ int part[256];
        int t = threadIdx.x;
        for (int g = 0; g < 2; g++) {
            int* st = (int*)(ws + (g ? WS_STARTF : WS_STARTB));
            int* cu = (int*)(ws + (g ? WS_PBF : WS_ACC));     // cursors alias dead regions
            int base = t * 64;
            int s = 0;
            for (int j = 0; j < 64; j++) s += st[base + j];
            part[t] = s;
            __syncthreads();
            if (t == 0) {
                int run = 0;
                for (int k = 0; k < 256; k++) { int v = part[k]; part[k] = run; run += v; }
            }
            __syncthreads();
            int off = part[t];
            for (int j = 0; j < 64; j++) {
                int c = st[base + j];
                st[base + j] = off; cu[base + j] = off; off += c;
            }
            if (t == 255) st[N_NODES] = off;
            __syncthreads();
        }
    }
}

// counting-sort step 3: scatter dst into src-sorted buckets
__global__ void k_sortscatter(const int* __restrict__ eib, const int* __restrict__ eif,
                              float* __restrict__ ws) {
    int e = blockIdx.x * blockDim.x + threadIdx.x;
    if (e < N_EDGES) {
        int s = eib[e], d = eib[N_EDGES + e];
        int* cur = (int*)(ws + WS_ACC);
        uint32_t* eb = (uint32_t*)(ws + WS_EDGEB);
        int pos = atomicAdd(&cur[s], 1);
        eb[pos] = (uint32_t)d;
    } else {
        int e2 = e - N_EDGES;
        if (e2 < N_EDGES) {
            int s = eif[e2], d = eif[N_EDGES + e2];
            int* cur = (int*)(ws + WS_PBF);
            uint32_t* ef = (uint32_t*)(ws + WS_EDGEF);
            int pos = atomicAdd(&cur[s], 1);
            ef[pos] = (uint32_t)d;
        }
    }
}

// per-node scalars (runs AFTER k_sortscatter; overwrites cursor aliases)
__global__ void k_nodes(const float* __restrict__ x, const float* __restrict__ prelu_a,
                        float* __restrict__ ws) {
    int i = blockIdx.x * blockDim.x + threadIdx.x;
    if (i >= N_NODES) return;
    const float* par = ws + WS_PAR;
    float alpha = prelu_a[0];
    float2 v = ((const float2*)x)[i];
    float p0 = par[193], pb = par[194], pf = par[195];
    #pragma unroll
    for (int j = 0; j < 32; j++) {
        float z = v.x * par[j] + v.y * par[32 + j] + par[64 + j];
        float h = z > 0.f ? z : alpha * z;
        p0 += h * par[96 + j];
        pb += h * par[128 + j];
        pf += h * par[160 + j];
    }
    ws[WS_ACC + i] = p0 + par[192];
    ((uint32_t*)(ws + WS_PBF))[i] = pack_h2(pb, pf);
}

// one wave per node row: L2-normalize, scale by 16, emit fp8. Body + face in one launch.
__global__ void k_normalize_all(const float* __restrict__ bfeat, const float* __restrict__ ffeat,
                                float* __restrict__ ws) {
    int wid  = (int)((blockIdx.x * blockDim.x + threadIdx.x) >> 6);
    int lane = threadIdx.x & 63;
    if (wid < N_NODES) {
        constexpr int L = DB / 512;                         // 4
        const float4* F = (const float4*)bfeat + (size_t)wid * (DB / 4);
        float4 va[L][2];
        float aa = 0.f;
        #pragma unroll
        for (int k = 0; k < L; k++) {
            float4 a0 = F[2 * lane + 128 * k];
            float4 a1 = F[2 * lane + 128 * k + 1];
            va[k][0] = a0; va[k][1] = a1;
            aa += a0.x * a0.x + a0.y * a0.y + a0.z * a0.z + a0.w * a0.w;
            aa += a1.x * a1.x + a1.y * a1.y + a1.z * a1.z + a1.w * a1.w;
        }
        #pragma unroll
        for (int off = 32; off; off >>= 1) aa += __shfl_xor(aa, off);
        float inv = rsqrtf(aa + 1e-12f) * FP8_SCALE;
        uint2* O = (uint2*)(ws + WS_FNB) + (size_t)wid * (DB / 8);
        #pragma unroll
        for (int k = 0; k < L; k++) {
            float4 a0 = va[k][0], a1 = va[k][1];
            uint2 o;
            o.x = pack4_fp8(a0.x * inv, a0.y * inv, a0.z * inv, a0.w * inv);
            o.y = pack4_fp8(a1.x * inv, a1.y * inv, a1.z * inv, a1.w * inv);
            O[lane + 64 * k] = o;
        }
    } else {
        int nid = wid - N_NODES;
        if (nid >= N_NODES) return;
        const float4* F = (const float4*)ffeat + (size_t)nid * (DF / 4);
        float4 a0 = F[2 * lane];
        float4 a1 = F[2 * lane + 1];
        float aa = a0.x * a0.x + a0.y * a0.y + a0.z * a0.z + a0.w * a0.w
                 + a1.x * a1.x + a1.y * a1.y + a1.z * a1.z + a1.w * a1.w;
        #pragma unroll
        for (int off = 32; off; off >>= 1) aa += __shfl_xor(aa, off);
        float inv = rsqrtf(aa + 1e-12f) * FP8_SCALE;
        uint2* O = (uint2*)(ws + WS_FNF) + (size_t)nid * (DF / 8);
        uint2 o;
        o.x = pack4_fp8(a0.x * inv, a0.y * inv, a0.z * inv, a0.w * inv);
        o.y = pack4_fp8(a1.x * inv, a1.y * inv, a1.z * inv, a1.w * inv);
        O[lane + 64 * 0] = o;
    }
}

// one wave per SRC node, both graphs in one launch. Body: 32B/lane rows (2 uint4).
// Face: 8B/lane rows (uint2), 4-edge unroll.
__global__ void k_edge_all(float* __restrict__ ws) {
    int wid  = (int)((blockIdx.x * blockDim.x + threadIdx.x) >> 6);
    int lane = threadIdx.x & 63;
    if (wid < N_NODES) {
        // ---- body ----
        const int* start = (const int*)(ws + WS_STARTB);
        uint32_t* edges  = (uint32_t*)(ws + WS_EDGEB);
        float* deg       = ws + WS_DEGB;
        int st = start[wid], en = start[wid + 1];
        if (st >= en) return;
        const uint4* fn = (const uint4*)(ws + WS_FNB);
        const uint4* S  = fn + (size_t)wid * 128;
        uint4 s0 = S[lane], s1 = S[lane + 64];
        float srcf[32];
        u32cvt(s0.x, srcf + 0);  u32cvt(s0.y, srcf + 4);
        u32cvt(s0.z, srcf + 8);  u32cvt(s0.w, srcf + 12);
        u32cvt(s1.x, srcf + 16); u32cvt(s1.y, srcf + 20);
        u32cvt(s1.z, srcf + 24); u32cvt(s1.w, srcf + 28);
        int i = st;
        for (; i + 1 < en; i += 2) {
            int dA = (int)(edges[i] & 0xFFFFu), dB = (int)(edges[i + 1] & 0xFFFFu);
            const uint4* A = fn + (size_t)dA * 128;
            const uint4* B = fn + (size_t)dB * 128;
            uint4 a0 = A[lane], a1 = A[lane + 64];
            uint4 b0 = B[lane], b1 = B[lane + 64];
            float da = 0.f, db = 0.f;
            da = dot16_fp8(a0, srcf, da); da = dot16_fp8(a1, srcf + 16, da);
            db = dot16_fp8(b0, srcf, db); db = dot16_fp8(b1, srcf + 16, db);
            #pragma unroll
            for (int off = 32; off; off >>= 1) {
                da += __shfl_xor(da, off); db += __shfl_xor(db, off);
            }
            if (lane == 0) {
                float sA = fmaxf(da, 0.f) * FP8_DESCALE;
                float sB = fmaxf(db, 0.f) * FP8_DESCALE;
                edges[i]     = (uint32_t)dA | ((uint32_t)f2h_bits(sA) << 16);
                edges[i + 1] = (uint32_t)dB | ((uint32_t)f2h_bits(sB) << 16);
                if (sA > 0.f) atomicAdd(&deg[dA], sA);
                if (sB > 0.f) atomicAdd(&deg[dB], sB);
            }
        }
        if (i < en) {
            int dA = (int)(edges[i] & 0xFFFFu);
            const uint4* A = fn + (size_t)dA * 128;
            uint4 a0 = A[lane], a1 = A[lane + 64];
            float da = 0.f;
            da = dot16_fp8(a0, srcf, da); da = dot16_fp8(a1, srcf + 16, da);
            #pragma unroll
            for (int off = 32; off; off >>= 1) da += __shfl_xor(da, off);
            if (lane == 0) {
                float sA = fmaxf(da, 0.f) * FP8_DESCALE;
                edges[i] = (uint32_t)dA | ((uint32_t)f2h_bits(sA) << 16);
                if (sA > 0.f) atomicAdd(&deg[dA], sA);
            }
        }
    } else {
        // ---- face ----
        int nid = wid - N_NODES;
        if (nid >= N_NODES) return;
        const int* start = (const int*)(ws + WS_STARTF);
        uint32_t* edges  = (uint32_t*)(ws + WS_EDGEF);
        float* deg       = ws + WS_DEGF;
        int st = start[nid], en = start[nid + 1];
        if (st >= en) return;
        const uint2* fn = (const uint2*)(ws + WS_FNF);
        uint2 sv = fn[(size_t)nid * 64 + lane];
        float srcf[8];
        u32cvt(sv.x, srcf); u32cvt(sv.y, srcf + 4);
        int i = st;
        for (; i + 3 < en; i += 4) {
            uint32_t w0 = edges[i], w1 = edges[i + 1], w2 = edges[i + 2], w3 = edges[i + 3];
            int d0 = (int)(w0 & 0xFFFFu), d1 = (int)(w1 & 0xFFFFu);
            int d2 = (int)(w2 & 0xFFFFu), d3 = (int)(w3 & 0xFFFFu);
            uint2 r0 = fn[(size_t)d0 * 64 + lane];
            uint2 r1 = fn[(size_t)d1 * 64 + lane];
            uint2 r2 = fn[(size_t)d2 * 64 + lane];
            uint2 r3 = fn[(size_t)d3 * 64 + lane];
            float c0 = u32dot(r0.y, srcf + 4, u32dot(r0.x, srcf, 0.f));
            float c1 = u32dot(r1.y, srcf + 4, u32dot(r1.x, srcf, 0.f));
            float c2 = u32dot(r2.y, srcf + 4, u32dot(r2.x, srcf, 0.f));
            float c3 = u32dot(r3.y, srcf + 4, u32dot(r3.x, srcf, 0.f));
            #pragma unroll
            for (int off = 32; off; off >>= 1) {
                c0 += __shfl_xor(c0, off); c1 += __shfl_xor(c1, off);
                c2 += __shfl_xor(c2, off); c3 += __shfl_xor(c3, off);
            }
            if (lane == 0) {
                float sm0 = fmaxf(c0, 0.f) * FP8_DESCALE;
                float sm1 = fmaxf(c1, 0.f) * FP8_DESCALE;
                float sm2 = fmaxf(c2, 0.f) * FP8_DESCALE;
                float sm3 = fmaxf(c3, 0.f) * FP8_DESCALE;
                edges[i]     = (uint32_t)d0 | ((uint32_t)f2h_bits(sm0) << 16);
                edges[i + 1] = (uint32_t)d1 | ((uint32_t)f2h_bits(sm1) << 16);
                edges[i + 2] = (uint32_t)d2 | ((uint32_t)f2h_bits(sm2) << 16);
                edges[i + 3] = (uint32_t)d3 | ((uint32_t)f2h_bits(sm3) << 16);
                if (sm0 > 0.f) atomicAdd(&deg[d0], sm0);
                if (sm1 > 0.f) atomicAdd(&deg[d1], sm1);
                if (sm2 > 0.f) atomicAdd(&deg[d2], sm2);
                if (sm3 > 0.f) atomicAdd(&deg[d3], sm3);
            }
        }
        for (; i < en; i++) {
            uint32_t w0 = edges[i];
            int d0 = (int)(w0 & 0xFFFFu);
            uint2 r0 = fn[(size_t)d0 * 64 + lane];
            float c0 = u32dot(r0.y, srcf + 4, u32dot(r0.x, srcf, 0.f));
            #pragma unroll
            for (int off = 32; off; off >>= 1) c0 += __shfl_xor(c0, off);
            if (lane == 0) {
                float sm0 = fmaxf(c0, 0.f) * FP8_DESCALE;
                edges[i] = (uint32_t)d0 | ((uint32_t)f2h_bits(sm0) << 16);
                if (sm0 > 0.f) atomicAdd(&deg[d0], sm0);
            }
        }
    }
}

__global__ void k_dn(float* __restrict__ ws) {
    int i = blockIdx.x * blockDim.x + threadIdx.x;
    if (i < 2 * N_NODES) {
        float* deg = ws + WS_DEGB;   // DEGB and DEGF contiguous
        deg[i] = rsqrtf(fmaxf(deg[i], 1e-6f));
    }
}

// one thread per (graph, src)
__global__ void k_scatter_grouped(float* __restrict__ ws) {
    int t = blockIdx.x * blockDim.x + threadIdx.x;
    if (t >= 2 * N_NODES) return;
    int s = t & (N_NODES - 1);
    int g = t >> 14;
    const int* start = (const int*)(ws + (g ? WS_STARTF : WS_STARTB));
    int st = start[s], en = start[s + 1];
    if (st >= en) return;
    const uint32_t* edges = (const uint32_t*)(ws + (g ? WS_EDGEF : WS_EDGEB));
    const float* dn = ws + (g ? WS_DEGF : WS_DEGB);
    uint32_t pk = ((const uint32_t*)(ws + WS_PBF))[s];
    float p = h_bits2f(g ? (uint16_t)(pk >> 16) : (uint16_t)(pk & 0xFFFFu));
    float c0 = dn[s] * p;
    float* acc = ws + WS_ACC;
    for (int e = st; e < en; e++) {
        uint32_t w = edges[e];
        float sm = h_bits2f((uint16_t)(w >> 16));
        if (sm > 0.f) {
            int d = (int)(w & 0xFFFFu);
            atomicAdd(&acc[d], c0 * dn[d] * sm);
        }
    }
}

__global__ void k_final(float* __restrict__ out, const float* __restrict__ ws) {
    int i = blockIdx.x * blockDim.x + threadIdx.x;
    if (i >= N_NODES) return;
    float dnb = ws[WS_DEGB + i];
    float dnf = ws[WS_DEGF + i];
    uint32_t pk = ((const uint32_t*)(ws + WS_PBF))[i];
    float pb = h_bits2f((uint16_t)(pk & 0xFFFFu));
    float pf = h_bits2f((uint16_t)(pk >> 16));
    out[i] = ws[WS_ACC + i] + dnb * dnb * pb + dnf * dnf * pf;
}

extern "C" void kernel_launch(void* const* d_in, const int* in_sizes, int n_in,
                              void* d_out, int out_size, void* d_ws, size_t ws_size,
                              hipStream_t stream) {
    const float* x     = (const float*)d_in[0];
    const float* bfeat = (const float*)d_in[1];
    const float* ffeat = (const float*)d_in[2];
    const int*   eib   = (const int*)d_in[3];
    const int*   eif   = (const int*)d_in[4];
    const float* w1    = (const float*)d_in[5];
    const float* b1    = (const float*)d_in[6];
    const float* gam   = (const float*)d_in[7];
    const float* bet   = (const float*)d_in[8];
    const float* pa    = (const float*)d_in[9];
    const float* w2    = (const float*)d_in[10];
    const float* b2    = (const float*)d_in[11];
    const float* w0w   = (const float*)d_in[12];
    const float* w0b   = (const float*)d_in[13];
    const float* gbw   = (const float*)d_in[14];
    const float* gbb   = (const float*)d_in[15];
    const float* gfw   = (const float*)d_in[16];
    const float* gfb   = (const float*)d_in[17];
    const float* wbw   = (const float*)d_in[18];
    const float* wbb   = (const float*)d_in[19];
    const float* wfw   = (const float*)d_in[20];
    const float* wfb   = (const float*)d_in[21];

    float* ws  = (float*)d_ws;
    float* out = (float*)d_out;

    k_pre<<<dim3(192), dim3(256), 0, stream>>>(x, ws);
    k_hist<<<dim3(1024), dim3(256), 0, stream>>>(eib, eif, ws);
    k_small<<<dim3(2), dim3(256), 0, stream>>>(w1, b1, gam, bet, w2, b2, w0w, w0b,
                                               gbw, gbb, gfw, gfb, wbw, wbb, wfw, wfb, ws);
    k_sortscatter<<<dim3(1024), dim3(256), 0, stream>>>(eib, eif, ws);
    k_nodes<<<dim3(N_NODES / 256), dim3(256), 0, stream>>>(x, pa, ws);
    k_normalize_all<<<dim3(2 * N_NODES / 4), dim3(256), 0, stream>>>(bfeat, ffeat, ws);
    k_edge_all<<<dim3(2 * N_NODES / 4), dim3(256), 0, stream>>>(ws);
    k_dn<<<dim3(128), dim3(256), 0, stream>>>(ws);
    k_scatter_grouped<<<dim3(128), dim3(256), 0, stream>>>(ws);
    k_final<<<dim3(N_NODES / 256), dim3(256), 0, stream>>>(out, ws);
}

// Round 5
// 172.285 us; speedup vs baseline: 2.5400x; 1.1451x over previous
//
#include <hip/hip_runtime.h>
#include <hip/hip_fp16.h>

#define N_NODES 16384
#define N_EDGES 131072
#define DB 2048
#define DF 512
#define FP8_SCALE 16.0f
#define FP8_DESCALE (1.0f / 256.0f)

// ---- workspace layout (float-unit offsets), ~43.6 MB ----
#define WS_STATS   0                               // 64 x 5 partials
#define WS_PAR     320                             // 256
#define WS_PBF     576                             // N packed (pb,pf) fp16
#define WS_DEGB    (WS_PBF + N_NODES)
#define WS_DEGF    (WS_DEGB + N_NODES)
#define WS_ACC     (WS_DEGF + N_NODES)             // p0 + C per node
#define WS_STARTB  (WS_ACC + N_NODES)              // N+4 ints (excl prefix of in-degree, [N]=E)
#define WS_STARTF  (WS_STARTB + N_NODES + 4)
#define WS_CURB    (WS_STARTF + N_NODES + 4)       // N ints (sort cursors)
#define WS_CURF    (WS_CURB + N_NODES)
#define WS_EDGEB   (WS_CURF + N_NODES)             // E words: src | (sim_fp16 << 16), dst-sorted
#define WS_EDGEF   (WS_EDGEB + N_EDGES)
#define WS_FNB     (WS_EDGEF + N_EDGES)            // N*DB fp8
#define WS_FNF     (WS_FNB + N_NODES * DB / 4)     // N*DF fp8

typedef float fv2 __attribute__((ext_vector_type(2)));

#if __has_builtin(__builtin_amdgcn_cvt_pk_f32_fp8) && __has_builtin(__builtin_amdgcn_cvt_pk_fp8_f32)
#define HAS_FP8HW 1
#else
#define HAS_FP8HW 0
#endif

// ---- fp16 helpers ----
__device__ __forceinline__ uint32_t pack_h2(float x, float y) {
    union { __half2 h; uint32_t u; } c; c.h = __floats2half2_rn(x, y); return c.u;
}
__device__ __forceinline__ uint16_t f2h_bits(float f) {
    union { __half h; uint16_t u; } c; c.h = __float2half_rn(f); return c.u;
}
__device__ __forceinline__ float h_bits2f(uint16_t u) {
    union { uint16_t u; __half h; } c; c.u = u; return __half2float(c.h);
}

// ---- fp8 e4m3 helpers ----
#if !HAS_FP8HW
__device__ __forceinline__ float fp8d_soft(uint32_t b) {
    uint32_t s = (b >> 7) & 1u, e = (b >> 3) & 0xFu, m = b & 7u;
    float v = (e == 0) ? (float)m * 0.001953125f
                       : (1.0f + (float)m * 0.125f) * exp2f((float)((int)e - 7));
    return s ? -v : v;
}
__device__ __forceinline__ uint32_t fp8e_soft(float f) {
    uint32_t s = (__float_as_uint(f) >> 31) << 7;
    float a = fabsf(f);
    if (a < 0.015625f) {
        int m = (int)rintf(a * 512.0f);
        if (m > 7) return s | (1u << 3);
        return s | (uint32_t)m;
    }
    uint32_t u = __float_as_uint(a);
    uint32_t r = u + 0x000FFFFFu + ((u >> 20) & 1u);
    int e8 = (int)(r >> 23) - 127 + 7;
    if (e8 >= 16) return s | (15u << 3) | 6u;
    return s | ((uint32_t)e8 << 3) | ((r >> 20) & 7u);
}
#endif

__device__ __forceinline__ float u32dot(uint32_t u, const float* s, float acc) {
#if HAS_FP8HW
    fv2 lo = __builtin_amdgcn_cvt_pk_f32_fp8(u, false);
    fv2 hi = __builtin_amdgcn_cvt_pk_f32_fp8(u, true);
    acc += s[0] * lo.x; acc += s[1] * lo.y;
    acc += s[2] * hi.x; acc += s[3] * hi.y;
#else
    acc += s[0] * fp8d_soft(u & 0xFF);
    acc += s[1] * fp8d_soft((u >> 8) & 0xFF);
    acc += s[2] * fp8d_soft((u >> 16) & 0xFF);
    acc += s[3] * fp8d_soft((u >> 24) & 0xFF);
#endif
    return acc;
}
__device__ __forceinline__ void u32cvt(uint32_t u, float* d) {
#if HAS_FP8HW
    fv2 lo = __builtin_amdgcn_cvt_pk_f32_fp8(u, false);
    fv2 hi = __builtin_amdgcn_cvt_pk_f32_fp8(u, true);
    d[0] = lo.x; d[1] = lo.y; d[2] = hi.x; d[3] = hi.y;
#else
    d[0] = fp8d_soft(u & 0xFF); d[1] = fp8d_soft((u >> 8) & 0xFF);
    d[2] = fp8d_soft((u >> 16) & 0xFF); d[3] = fp8d_soft((u >> 24) & 0xFF);
#endif
}
__device__ __forceinline__ uint32_t pack4_fp8(float a, float b, float c, float d) {
#if HAS_FP8HW
    uint32_t u = 0;
    u = __builtin_amdgcn_cvt_pk_fp8_f32(a, b, u, false);
    u = __builtin_amdgcn_cvt_pk_fp8_f32(c, d, u, true);
    return u;
#else
    return fp8e_soft(a) | (fp8e_soft(b) << 8) | (fp8e_soft(c) << 16) | (fp8e_soft(d) << 24);
#endif
}
__device__ __forceinline__ float dot16_fp8(uint4 r, const float* s, float acc) {
    acc = u32dot(r.x, s + 0, acc);  acc = u32dot(r.y, s + 4, acc);
    acc = u32dot(r.z, s + 8, acc);  acc = u32dot(r.w, s + 12, acc);
    return acc;
}

// ---- launch 1: x-stats partials (blocks 0..63) + init (blocks 64..191) ----
__global__ void k_pre(const float* __restrict__ x, float* __restrict__ ws) {
    if (blockIdx.x < 64) {
        float s0 = 0.f, s1 = 0.f, s2 = 0.f, s3 = 0.f, s4 = 0.f;
        for (int i = blockIdx.x * 256 + threadIdx.x; i < N_NODES; i += 64 * 256) {
            float2 v = ((const float2*)x)[i];
            s0 += v.x; s1 += v.y;
            s2 += v.x * v.x; s3 += v.y * v.y; s4 += v.x * v.y;
        }
        #pragma unroll
        for (int off = 32; off; off >>= 1) {
            s0 += __shfl_down(s0, off); s1 += __shfl_down(s1, off);
            s2 += __shfl_down(s2, off); s3 += __shfl_down(s3, off);
            s4 += __shfl_down(s4, off);
        }
        __shared__ float red[4][5];
        int w = threadIdx.x >> 6;
        if ((threadIdx.x & 63) == 0) {
            red[w][0] = s0; red[w][1] = s1; red[w][2] = s2; red[w][3] = s3; red[w][4] = s4;
        }
        __syncthreads();
        if (threadIdx.x < 5) {
            ws[WS_STATS + blockIdx.x * 5 + threadIdx.x] =
                red[0][threadIdx.x] + red[1][threadIdx.x] +
                red[2][threadIdx.x] + red[3][threadIdx.x];
        }
    } else {
        int j = (blockIdx.x - 64) * 256 + threadIdx.x;   // [0, 32768)
        int* sb = (int*)(ws + WS_STARTB);
        int* sf = (int*)(ws + WS_STARTF);
        if (j < N_NODES + 4) { sb[j] = 0; sf[j] = 0; }
        ws[WS_DEGB + j] = 1.f;     // DEGB then DEGF (contiguous 2N)
    }
}

// ---- launch 2: in-degree histogram (by DST) ----
__global__ void k_hist(const int* __restrict__ eib, const int* __restrict__ eif,
                       float* __restrict__ ws) {
    int e = blockIdx.x * blockDim.x + threadIdx.x;
    if (e < N_EDGES) {
        atomicAdd(&((int*)(ws + WS_STARTB))[eib[N_EDGES + e]], 1);
    } else {
        int e2 = e - N_EDGES;
        atomicAdd(&((int*)(ws + WS_STARTF))[eif[N_EDGES + e2]], 1);
    }
}

// ---- launch 3: block 0 = prefix scan (both graphs); block 1 = closed-form params ----
__global__ void k_scan(const float* __restrict__ w1, const float* __restrict__ b1,
                       const float* __restrict__ gamma, const float* __restrict__ beta,
                       const float* __restrict__ w2, const float* __restrict__ b2,
                       const float* __restrict__ w0w, const float* __restrict__ w0b,
                       const float* __restrict__ gbw, const float* __restrict__ gbb,
                       const float* __restrict__ gfw, const float* __restrict__ gfb,
                       const float* __restrict__ wbw, const float* __restrict__ wbb,
                       const float* __restrict__ wfw, const float* __restrict__ wfb,
                       float* __restrict__ ws) {
    if (blockIdx.x == 0) {
        __shared__ int wsum[4];
        int t = threadIdx.x;
        int lane = t & 63, w = t >> 6;
        for (int g = 0; g < 2; g++) {
            int* st = (int*)(ws + (g ? WS_STARTF : WS_STARTB));
            int* cu = (int*)(ws + (g ? WS_CURF : WS_CURB));
            int base = t * 64;
            int csum = 0;
            for (int j = 0; j < 64; j++) csum += st[base + j];
            int v = csum;
            #pragma unroll
            for (int off = 1; off < 64; off <<= 1) {
                int n = __shfl_up(v, off);
                if (lane >= off) v += n;
            }
            if (lane == 63) wsum[w] = v;
            __syncthreads();
            int add = 0;
            for (int k = 0; k < w; k++) add += wsum[k];
            int run = v + add - csum;         // exclusive prefix of this chunk
            for (int j = 0; j < 64; j++) {
                int c = st[base + j];
                st[base + j] = run; cu[base + j] = run; run += c;
            }
            if (t == 255) st[N_NODES] = run;
            __syncthreads();
        }
    } else {
        __shared__ float st5[5];
        if (threadIdx.x < 5) {
            float t = 0.f;
            for (int b = 0; b < 64; b++) t += ws[WS_STATS + b * 5 + threadIdx.x];
            st5[threadIdx.x] = t;
        }
        __syncthreads();
        const float inv_n = 1.0f / (float)N_NODES;
        float m0 = st5[0] * inv_n, m1 = st5[1] * inv_n;
        float v0 = st5[2] * inv_n - m0 * m0;
        float v1 = st5[3] * inv_n - m1 * m1;
        float cv = st5[4] * inv_n - m0 * m1;
        float* par = ws + WS_PAR;
        int j = threadIdx.x;
        if (j < 32) {
            float W0 = w1[j], W1 = w1[32 + j];
            float mu  = m0 * W0 + m1 * W1 + b1[j];
            float var = W0 * W0 * v0 + W1 * W1 * v1 + 2.f * W0 * W1 * cv;
            float is  = rsqrtf(var + 1e-5f) * gamma[j];
            par[j]      = W0 * is;
            par[32 + j] = W1 * is;
            par[64 + j] = (b1[j] - mu) * is + beta[j];
            float u0 = 0.f, ub = 0.f, uf = 0.f;
            for (int k = 0; k < 32; k++) {
                float w2jk = w2[j * 32 + k];
                float vbk = 0.f, vfk = 0.f;
                for (int n = 0; n < 32; n++) {
                    vbk += gbw[k * 32 + n] * wbw[n];
                    vfk += gfw[k * 32 + n] * wfw[n];
                }
                u0 += w2jk * w0w[k];
                ub += w2jk * vbk;
                uf += w2jk * vfk;
            }
            par[96 + j]  = u0;
            par[128 + j] = ub;
            par[160 + j] = uf;
        }
        if (threadIdx.x == 0) {
            float C = w0b[0] + wbb[0] + wfb[0];
            float pc0 = 0.f, pcb = 0.f, pcf = 0.f;
            for (int k = 0; k < 32; k++) {
                float vbk = 0.f, vfk = 0.f;
                for (int n = 0; n < 32; n++) {
                    vbk += gbw[k * 32 + n] * wbw[n];
                    vfk += gfw[k * 32 + n] * wfw[n];
                }
                pc0 += b2[k] * w0w[k];
                pcb += b2[k] * vbk;
                pcf += b2[k] * vfk;
                C   += gbb[k] * wbw[k] + gfb[k] * wfw[k];
            }
            par[192] = C; par[193] = pc0; par[194] = pcb; par[195] = pcf;
        }
    }
}

// ---- launch 4: sortscatter (blocks 0..1023) + node scalars (1024..1087) + normalize (1088..9279) ----
__global__ void k_big(const int* __restrict__ eib, const int* __restrict__ eif,
                      const float* __restrict__ x, const float* __restrict__ prelu_a,
                      const float* __restrict__ bfeat, const float* __restrict__ ffeat,
                      float* __restrict__ ws) {
    int b = blockIdx.x;
    if (b < 1024) {
        int e = b * 256 + threadIdx.x;          // [0, 2E)
        if (e < N_EDGES) {
            int s = eib[e], d = eib[N_EDGES + e];
            int pos = atomicAdd(&((int*)(ws + WS_CURB))[d], 1);
            ((uint32_t*)(ws + WS_EDGEB))[pos] = (uint32_t)s;
        } else {
            int e2 = e - N_EDGES;
            int s = eif[e2], d = eif[N_EDGES + e2];
            int pos = atomicAdd(&((int*)(ws + WS_CURF))[d], 1);
            ((uint32_t*)(ws + WS_EDGEF))[pos] = (uint32_t)s;
        }
    } else if (b < 1088) {
        int i = (b - 1024) * 256 + threadIdx.x;
        if (i >= N_NODES) return;
        const float* par = ws + WS_PAR;
        float alpha = prelu_a[0];
        float2 v = ((const float2*)x)[i];
        float p0 = par[193], pb = par[194], pf = par[195];
        #pragma unroll
        for (int j = 0; j < 32; j++) {
            float z = v.x * par[j] + v.y * par[32 + j] + par[64 + j];
            float h = z > 0.f ? z : alpha * z;
            p0 += h * par[96 + j];
            pb += h * par[128 + j];
            pf += h * par[160 + j];
        }
        ws[WS_ACC + i] = p0 + par[192];
        ((uint32_t*)(ws + WS_PBF))[i] = pack_h2(pb, pf);
    } else {
        int idx = (b - 1088) * 256 + threadIdx.x;
        int wid  = idx >> 6;
        int lane = idx & 63;
        if (wid < N_NODES) {
            constexpr int L = DB / 512;                     // 4
            const float4* F = (const float4*)bfeat + (size_t)wid * (DB / 4);
            float4 va[L][2];
            float aa = 0.f;
            #pragma unroll
            for (int k = 0; k < L; k++) {
                float4 a0 = F[2 * lane + 128 * k];
                float4 a1 = F[2 * lane + 128 * k + 1];
                va[k][0] = a0; va[k][1] = a1;
                aa += a0.x * a0.x + a0.y * a0.y + a0.z * a0.z + a0.w * a0.w;
                aa += a1.x * a1.x + a1.y * a1.y + a1.z * a1.z + a1.w * a1.w;
            }
            #pragma unroll
            for (int off = 32; off; off >>= 1) aa += __shfl_xor(aa, off);
            float inv = rsqrtf(aa + 1e-12f) * FP8_SCALE;
            uint2* O = (uint2*)(ws + WS_FNB) + (size_t)wid * (DB / 8);
            #pragma unroll
            for (int k = 0; k < L; k++) {
                float4 a0 = va[k][0], a1 = va[k][1];
                uint2 o;
                o.x = pack4_fp8(a0.x * inv, a0.y * inv, a0.z * inv, a0.w * inv);
                o.y = pack4_fp8(a1.x * inv, a1.y * inv, a1.z * inv, a1.w * inv);
                O[lane + 64 * k] = o;
            }
        } else {
            int nid = wid - N_NODES;
            if (nid >= N_NODES) return;
            const float4* F = (const float4*)ffeat + (size_t)nid * (DF / 4);
            float4 a0 = F[2 * lane];
            float4 a1 = F[2 * lane + 1];
            float aa = a0.x * a0.x + a0.y * a0.y + a0.z * a0.z + a0.w * a0.w
                     + a1.x * a1.x + a1.y * a1.y + a1.z * a1.z + a1.w * a1.w;
            #pragma unroll
            for (int off = 32; off; off >>= 1) aa += __shfl_xor(aa, off);
            float inv = rsqrtf(aa + 1e-12f) * FP8_SCALE;
            uint2* O = (uint2*)(ws + WS_FNF) + (size_t)nid * (DF / 8);
            uint2 o;
            o.x = pack4_fp8(a0.x * inv, a0.y * inv, a0.z * inv, a0.w * inv);
            o.y = pack4_fp8(a1.x * inv, a1.y * inv, a1.z * inv, a1.w * inv);
            O[lane] = o;
        }
    }
}

// ---- launch 5: one wave per DST node; dst row in regs; gather src rows.
// deg[d] written non-atomically (single owner wave). sims stored into edge words. ----
__global__ void k_edge_all(float* __restrict__ ws) {
    int wid  = (int)((blockIdx.x * blockDim.x + threadIdx.x) >> 6);
    int lane = threadIdx.x & 63;
    if (wid < N_NODES) {
        const int* start = (const int*)(ws + WS_STARTB);
        uint32_t* edges  = (uint32_t*)(ws + WS_EDGEB);
        int st = start[wid], en = start[wid + 1];
        if (st >= en) return;
        const uint4* fn = (const uint4*)(ws + WS_FNB);
        const uint4* Dp = fn + (size_t)wid * 128;
        uint4 r0 = Dp[lane], r1 = Dp[lane + 64];
        float dstf[32];
        u32cvt(r0.x, dstf + 0);  u32cvt(r0.y, dstf + 4);
        u32cvt(r0.z, dstf + 8);  u32cvt(r0.w, dstf + 12);
        u32cvt(r1.x, dstf + 16); u32cvt(r1.y, dstf + 20);
        u32cvt(r1.z, dstf + 24); u32cvt(r1.w, dstf + 28);
        float wdeg = 0.f;
        int i = st;
        for (; i + 3 < en; i += 4) {
            uint32_t w0 = edges[i], w1 = edges[i + 1], w2 = edges[i + 2], w3 = edges[i + 3];
            const uint4* A = fn + (size_t)(w0 & 0xFFFFu) * 128;
            const uint4* B = fn + (size_t)(w1 & 0xFFFFu) * 128;
            const uint4* C = fn + (size_t)(w2 & 0xFFFFu) * 128;
            const uint4* E = fn + (size_t)(w3 & 0xFFFFu) * 128;
            uint4 a0 = A[lane], a1 = A[lane + 64];
            uint4 b0 = B[lane], b1 = B[lane + 64];
            uint4 c0 = C[lane], c1 = C[lane + 64];
            uint4 e0 = E[lane], e1 = E[lane + 64];
            float s0 = 0.f, s1 = 0.f, s2 = 0.f, s3 = 0.f;
            s0 = dot16_fp8(a0, dstf, s0); s0 = dot16_fp8(a1, dstf + 16, s0);
            s1 = dot16_fp8(b0, dstf, s1); s1 = dot16_fp8(b1, dstf + 16, s1);
            s2 = dot16_fp8(c0, dstf, s2); s2 = dot16_fp8(c1, dstf + 16, s2);
            s3 = dot16_fp8(e0, dstf, s3); s3 = dot16_fp8(e1, dstf + 16, s3);
            #pragma unroll
            for (int off = 32; off; off >>= 1) {
                s0 += __shfl_xor(s0, off); s1 += __shfl_xor(s1, off);
                s2 += __shfl_xor(s2, off); s3 += __shfl_xor(s3, off);
            }
            if (lane == 0) {
                float m0 = fmaxf(s0, 0.f) * FP8_DESCALE;
                float m1 = fmaxf(s1, 0.f) * FP8_DESCALE;
                float m2 = fmaxf(s2, 0.f) * FP8_DESCALE;
                float m3 = fmaxf(s3, 0.f) * FP8_DESCALE;
                edges[i]     = (w0 & 0xFFFFu) | ((uint32_t)f2h_bits(m0) << 16);
                edges[i + 1] = (w1 & 0xFFFFu) | ((uint32_t)f2h_bits(m1) << 16);
                edges[i + 2] = (w2 & 0xFFFFu) | ((uint32_t)f2h_bits(m2) << 16);
                edges[i + 3] = (w3 & 0xFFFFu) | ((uint32_t)f2h_bits(m3) << 16);
                wdeg += m0 + m1 + m2 + m3;
            }
        }
        for (; i < en; i++) {
            uint32_t w0 = edges[i];
            const uint4* A = fn + (size_t)(w0 & 0xFFFFu) * 128;
            uint4 a0 = A[lane], a1 = A[lane + 64];
            float s0 = 0.f;
            s0 = dot16_fp8(a0, dstf, s0); s0 = dot16_fp8(a1, dstf + 16, s0);
            #pragma unroll
            for (int off = 32; off; off >>= 1) s0 += __shfl_xor(s0, off);
            if (lane == 0) {
                float m0 = fmaxf(s0, 0.f) * FP8_DESCALE;
                edges[i] = (w0 & 0xFFFFu) | ((uint32_t)f2h_bits(m0) << 16);
                wdeg += m0;
            }
        }
        if (lane == 0) ws[WS_DEGB + wid] = 1.f + wdeg;
    } else {
        int nid = wid - N_NODES;
        if (nid >= N_NODES) return;
        const int* start = (const int*)(ws + WS_STARTF);
        uint32_t* edges  = (uint32_t*)(ws + WS_EDGEF);
        int st = start[nid], en = start[nid + 1];
        if (st >= en) return;
        const uint2* fn = (const uint2*)(ws + WS_FNF);
        uint2 sv = fn[(size_t)nid * 64 + lane];
        float dstf[8];
        u32cvt(sv.x, dstf); u32cvt(sv.y, dstf + 4);
        float wdeg = 0.f;
        int i = st;
        for (; i + 3 < en; i += 4) {
            uint32_t w0 = edges[i], w1 = edges[i + 1], w2 = edges[i + 2], w3 = edges[i + 3];
            uint2 r0 = fn[(size_t)(w0 & 0xFFFFu) * 64 + lane];
            uint2 r1 = fn[(size_t)(w1 & 0xFFFFu) * 64 + lane];
            uint2 r2 = fn[(size_t)(w2 & 0xFFFFu) * 64 + lane];
            uint2 r3 = fn[(size_t)(w3 & 0xFFFFu) * 64 + lane];
            float c0 = u32dot(r0.y, dstf + 4, u32dot(r0.x, dstf, 0.f));
            float c1 = u32dot(r1.y, dstf + 4, u32dot(r1.x, dstf, 0.f));
            float c2 = u32dot(r2.y, dstf + 4, u32dot(r2.x, dstf, 0.f));
            float c3 = u32dot(r3.y, dstf + 4, u32dot(r3.x, dstf, 0.f));
            #pragma unroll
            for (int off = 32; off; off >>= 1) {
                c0 += __shfl_xor(c0, off); c1 += __shfl_xor(c1, off);
                c2 += __shfl_xor(c2, off); c3 += __shfl_xor(c3, off);
            }
            if (lane == 0) {
                float m0 = fmaxf(c0, 0.f) * FP8_DESCALE;
                float m1 = fmaxf(c1, 0.f) * FP8_DESCALE;
                float m2 = fmaxf(c2, 0.f) * FP8_DESCALE;
                float m3 = fmaxf(c3, 0.f) * FP8_DESCALE;
                edges[i]     = (w0 & 0xFFFFu) | ((uint32_t)f2h_bits(m0) << 16);
                edges[i + 1] = (w1 & 0xFFFFu) | ((uint32_t)f2h_bits(m1) << 16);
                edges[i + 2] = (w2 & 0xFFFFu) | ((uint32_t)f2h_bits(m2) << 16);
                edges[i + 3] = (w3 & 0xFFFFu) | ((uint32_t)f2h_bits(m3) << 16);
                wdeg += m0 + m1 + m2 + m3;
            }
        }
        for (; i < en; i++) {
            uint32_t w0 = edges[i];
            uint2 r0 = fn[(size_t)(w0 & 0xFFFFu) * 64 + lane];
            float c0 = u32dot(r0.y, dstf + 4, u32dot(r0.x, dstf, 0.f));
            #pragma unroll
            for (int off = 32; off; off >>= 1) c0 += __shfl_xor(c0, off);
            if (lane == 0) {
                float m0 = fmaxf(c0, 0.f) * FP8_DESCALE;
                edges[i] = (w0 & 0xFFFFu) | ((uint32_t)f2h_bits(m0) << 16);
                wdeg += m0;
            }
        }
        if (lane == 0) ws[WS_DEGF + nid] = 1.f + wdeg;
    }
}

// ---- launch 6: per-dst pull (no atomics) + final combine ----
__global__ void k_out(float* __restrict__ out, const float* __restrict__ ws) {
    int i = blockIdx.x * blockDim.x + threadIdx.x;
    if (i >= N_NODES) return;
    const uint32_t* pk = (const uint32_t*)(ws + WS_PBF);
    uint32_t pme = pk[i];
    float pb = h_bits2f((uint16_t)(pme & 0xFFFFu));
    float pf = h_bits2f((uint16_t)(pme >> 16));
    float dnb = rsqrtf(fmaxf(ws[WS_DEGB + i], 1e-6f));
    float dnf = rsqrtf(fmaxf(ws[WS_DEGF + i], 1e-6f));

    const int* stb = (const int*)(ws + WS_STARTB);
    const uint32_t* eb = (const uint32_t*)(ws + WS_EDGEB);
    float sumb = 0.f;
    for (int e = stb[i]; e < stb[i + 1]; e++) {
        uint32_t w = eb[e];
        float sm = h_bits2f((uint16_t)(w >> 16));
        if (sm > 0.f) {
            int s = (int)(w & 0xFFFFu);
            float ps = h_bits2f((uint16_t)(pk[s] & 0xFFFFu));
            sumb += rsqrtf(fmaxf(ws[WS_DEGB + s], 1e-6f)) * sm * ps;
        }
    }
    const int* stf = (const int*)(ws + WS_STARTF);
    const uint32_t* ef = (const uint32_t*)(ws + WS_EDGEF);
    float sumf = 0.f;
    for (int e = stf[i]; e < stf[i + 1]; e++) {
        uint32_t w = ef[e];
        float sm = h_bits2f((uint16_t)(w >> 16));
        if (sm > 0.f) {
            int s = (int)(w & 0xFFFFu);
            float ps = h_bits2f((uint16_t)(pk[s] >> 16));
            sumf += rsqrtf(fmaxf(ws[WS_DEGF + s], 1e-6f)) * sm * ps;
        }
    }
    out[i] = ws[WS_ACC + i] + dnb * (dnb * pb + sumb) + dnf * (dnf * pf + sumf);
}

extern "C" void kernel_launch(void* const* d_in, const int* in_sizes, int n_in,
                              void* d_out, int out_size, void* d_ws, size_t ws_size,
                              hipStream_t stream) {
    const float* x     = (const float*)d_in[0];
    const float* bfeat = (const float*)d_in[1];
    const float* ffeat = (const float*)d_in[2];
    const int*   eib   = (const int*)d_in[3];
    const int*   eif   = (const int*)d_in[4];
    const float* w1    = (const float*)d_in[5];
    const float* b1    = (const float*)d_in[6];
    const float* gam   = (const float*)d_in[7];
    const float* bet   = (const float*)d_in[8];
    const float* pa    = (const float*)d_in[9];
    const float* w2    = (const float*)d_in[10];
    const float* b2    = (const float*)d_in[11];
    const float* w0w   = (const float*)d_in[12];
    const float* w0b   = (const float*)d_in[13];
    const float* gbw   = (const float*)d_in[14];
    const float* gbb   = (const float*)d_in[15];
    const float* gfw   = (const float*)d_in[16];
    const float* gfb   = (const float*)d_in[17];
    const float* wbw   = (const float*)d_in[18];
    const float* wbb   = (const float*)d_in[19];
    const float* wfw   = (const float*)d_in[20];
    const float* wfb   = (const float*)d_in[21];

    float* ws  = (float*)d_ws;
    float* out = (float*)d_out;

    k_pre<<<dim3(192), dim3(256), 0, stream>>>(x, ws);
    k_hist<<<dim3(1024), dim3(256), 0, stream>>>(eib, eif, ws);
    k_scan<<<dim3(2), dim3(256), 0, stream>>>(w1, b1, gam, bet, w2, b2, w0w, w0b,
                                              gbw, gbb, gfw, gfb, wbw, wbb, wfw, wfb, ws);
    k_big<<<dim3(9280), dim3(256), 0, stream>>>(eib, eif, x, pa, bfeat, ffeat, ws);
    k_edge_all<<<dim3(2 * N_NODES / 4), dim3(256), 0, stream>>>(ws);
    k_out<<<dim3(N_NODES / 256), dim3(256), 0, stream>>>(out, ws);
}

// Round 6
// 165.868 us; speedup vs baseline: 2.6383x; 1.0387x over previous
//
#include <hip/hip_runtime.h>
#include <hip/hip_fp16.h>

#define N_NODES 16384
#define N_EDGES 131072
#define DB 2048
#define DF 512
#define FP8_SCALE 16.0f
#define FP8_DESCALE (1.0f / 256.0f)

// ---- workspace layout (float-unit offsets), ~43.6 MB ----
#define WS_STATS   0                               // 64 x 5 partials
#define WS_PAR     320                             // 256
#define WS_PBF     576                             // N packed (pb,pf) fp16
#define WS_DEGB    (WS_PBF + N_NODES)
#define WS_DEGF    (WS_DEGB + N_NODES)
#define WS_ACC     (WS_DEGF + N_NODES)             // p0 + C per node
#define WS_STARTB  (WS_ACC + N_NODES)              // N+4 ints (excl prefix of in-degree, [N]=E)
#define WS_STARTF  (WS_STARTB + N_NODES + 4)
#define WS_CURB    (WS_STARTF + N_NODES + 4)       // N ints (sort cursors)
#define WS_CURF    (WS_CURB + N_NODES)
#define WS_EDGEB   (WS_CURF + N_NODES)             // E words: src | (sim_fp16 << 16), dst-sorted
#define WS_EDGEF   (WS_EDGEB + N_EDGES)
#define WS_FNB     (WS_EDGEF + N_EDGES)            // N*DB fp8
#define WS_FNF     (WS_FNB + N_NODES * DB / 4)     // N*DF fp8

typedef float fv2 __attribute__((ext_vector_type(2)));

#if __has_builtin(__builtin_amdgcn_cvt_pk_f32_fp8) && __has_builtin(__builtin_amdgcn_cvt_pk_fp8_f32)
#define HAS_FP8HW 1
#else
#define HAS_FP8HW 0
#endif

// ---- fp16 helpers ----
__device__ __forceinline__ uint32_t pack_h2(float x, float y) {
    union { __half2 h; uint32_t u; } c; c.h = __floats2half2_rn(x, y); return c.u;
}
__device__ __forceinline__ uint16_t f2h_bits(float f) {
    union { __half h; uint16_t u; } c; c.h = __float2half_rn(f); return c.u;
}
__device__ __forceinline__ float h_bits2f(uint16_t u) {
    union { uint16_t u; __half h; } c; c.u = u; return __half2float(c.h);
}

// ---- fp8 e4m3 helpers ----
#if !HAS_FP8HW
__device__ __forceinline__ float fp8d_soft(uint32_t b) {
    uint32_t s = (b >> 7) & 1u, e = (b >> 3) & 0xFu, m = b & 7u;
    float v = (e == 0) ? (float)m * 0.001953125f
                       : (1.0f + (float)m * 0.125f) * exp2f((float)((int)e - 7));
    return s ? -v : v;
}
__device__ __forceinline__ uint32_t fp8e_soft(float f) {
    uint32_t s = (__float_as_uint(f) >> 31) << 7;
    float a = fabsf(f);
    if (a < 0.015625f) {
        int m = (int)rintf(a * 512.0f);
        if (m > 7) return s | (1u << 3);
        return s | (uint32_t)m;
    }
    uint32_t u = __float_as_uint(a);
    uint32_t r = u + 0x000FFFFFu + ((u >> 20) & 1u);
    int e8 = (int)(r >> 23) - 127 + 7;
    if (e8 >= 16) return s | (15u << 3) | 6u;
    return s | ((uint32_t)e8 << 3) | ((r >> 20) & 7u);
}
#endif

__device__ __forceinline__ float u32dot(uint32_t u, const float* s, float acc) {
#if HAS_FP8HW
    fv2 lo = __builtin_amdgcn_cvt_pk_f32_fp8(u, false);
    fv2 hi = __builtin_amdgcn_cvt_pk_f32_fp8(u, true);
    acc += s[0] * lo.x; acc += s[1] * lo.y;
    acc += s[2] * hi.x; acc += s[3] * hi.y;
#else
    acc += s[0] * fp8d_soft(u & 0xFF);
    acc += s[1] * fp8d_soft((u >> 8) & 0xFF);
    acc += s[2] * fp8d_soft((u >> 16) & 0xFF);
    acc += s[3] * fp8d_soft((u >> 24) & 0xFF);
#endif
    return acc;
}
__device__ __forceinline__ void u32cvt(uint32_t u, float* d) {
#if HAS_FP8HW
    fv2 lo = __builtin_amdgcn_cvt_pk_f32_fp8(u, false);
    fv2 hi = __builtin_amdgcn_cvt_pk_f32_fp8(u, true);
    d[0] = lo.x; d[1] = lo.y; d[2] = hi.x; d[3] = hi.y;
#else
    d[0] = fp8d_soft(u & 0xFF); d[1] = fp8d_soft((u >> 8) & 0xFF);
    d[2] = fp8d_soft((u >> 16) & 0xFF); d[3] = fp8d_soft((u >> 24) & 0xFF);
#endif
}
__device__ __forceinline__ uint32_t pack4_fp8(float a, float b, float c, float d) {
#if HAS_FP8HW
    uint32_t u = 0;
    u = __builtin_amdgcn_cvt_pk_fp8_f32(a, b, u, false);
    u = __builtin_amdgcn_cvt_pk_fp8_f32(c, d, u, true);
    return u;
#else
    return fp8e_soft(a) | (fp8e_soft(b) << 8) | (fp8e_soft(c) << 16) | (fp8e_soft(d) << 24);
#endif
}
__device__ __forceinline__ float dot16_fp8(uint4 r, const float* s, float acc) {
    acc = u32dot(r.x, s + 0, acc);  acc = u32dot(r.y, s + 4, acc);
    acc = u32dot(r.z, s + 8, acc);  acc = u32dot(r.w, s + 12, acc);
    return acc;
}

// ---- launch 1: x-stats partials (blocks 0..63) + init (blocks 64..191) ----
__global__ void k_pre(const float* __restrict__ x, float* __restrict__ ws) {
    if (blockIdx.x < 64) {
        float s0 = 0.f, s1 = 0.f, s2 = 0.f, s3 = 0.f, s4 = 0.f;
        for (int i = blockIdx.x * 256 + threadIdx.x; i < N_NODES; i += 64 * 256) {
            float2 v = ((const float2*)x)[i];
            s0 += v.x; s1 += v.y;
            s2 += v.x * v.x; s3 += v.y * v.y; s4 += v.x * v.y;
        }
        #pragma unroll
        for (int off = 32; off; off >>= 1) {
            s0 += __shfl_down(s0, off); s1 += __shfl_down(s1, off);
            s2 += __shfl_down(s2, off); s3 += __shfl_down(s3, off);
            s4 += __shfl_down(s4, off);
        }
        __shared__ float red[4][5];
        int w = threadIdx.x >> 6;
        if ((threadIdx.x & 63) == 0) {
            red[w][0] = s0; red[w][1] = s1; red[w][2] = s2; red[w][3] = s3; red[w][4] = s4;
        }
        __syncthreads();
        if (threadIdx.x < 5) {
            ws[WS_STATS + blockIdx.x * 5 + threadIdx.x] =
                red[0][threadIdx.x] + red[1][threadIdx.x] +
                red[2][threadIdx.x] + red[3][threadIdx.x];
        }
    } else {
        int j = (blockIdx.x - 64) * 256 + threadIdx.x;   // [0, 32768)
        int* sb = (int*)(ws + WS_STARTB);
        int* sf = (int*)(ws + WS_STARTF);
        if (j < N_NODES + 4) { sb[j] = 0; sf[j] = 0; }
        ws[WS_DEGB + j] = 1.f;     // DEGB then DEGF (contiguous 2N)
    }
}

// ---- launch 2: in-degree histogram (by DST) ----
__global__ void k_hist(const int* __restrict__ eib, const int* __restrict__ eif,
                       float* __restrict__ ws) {
    int e = blockIdx.x * blockDim.x + threadIdx.x;
    if (e < N_EDGES) {
        atomicAdd(&((int*)(ws + WS_STARTB))[eib[N_EDGES + e]], 1);
    } else {
        int e2 = e - N_EDGES;
        atomicAdd(&((int*)(ws + WS_STARTF))[eif[N_EDGES + e2]], 1);
    }
}

// ---- launch 3: block 0 = prefix scan (both graphs); block 1 = closed-form params ----
__global__ void k_scan(const float* __restrict__ w1, const float* __restrict__ b1,
                       const float* __restrict__ gamma, const float* __restrict__ beta,
                       const float* __restrict__ w2, const float* __restrict__ b2,
                       const float* __restrict__ w0w, const float* __restrict__ w0b,
                       const float* __restrict__ gbw, const float* __restrict__ gbb,
                       const float* __restrict__ gfw, const float* __restrict__ gfb,
                       const float* __restrict__ wbw, const float* __restrict__ wbb,
                       const float* __restrict__ wfw, const float* __restrict__ wfb,
                       float* __restrict__ ws) {
    if (blockIdx.x == 0) {
        __shared__ int wsum[4];
        int t = threadIdx.x;
        int lane = t & 63, w = t >> 6;
        for (int g = 0; g < 2; g++) {
            int* st = (int*)(ws + (g ? WS_STARTF : WS_STARTB));
            int* cu = (int*)(ws + (g ? WS_CURF : WS_CURB));
            int base = t * 64;
            int csum = 0;
            for (int j = 0; j < 64; j++) csum += st[base + j];
            int v = csum;
            #pragma unroll
            for (int off = 1; off < 64; off <<= 1) {
                int n = __shfl_up(v, off);
                if (lane >= off) v += n;
            }
            if (lane == 63) wsum[w] = v;
            __syncthreads();
            int add = 0;
            for (int k = 0; k < w; k++) add += wsum[k];
            int run = v + add - csum;         // exclusive prefix of this chunk
            for (int j = 0; j < 64; j++) {
                int c = st[base + j];
                st[base + j] = run; cu[base + j] = run; run += c;
            }
            if (t == 255) st[N_NODES] = run;
            __syncthreads();
        }
    } else {
        __shared__ float st5[5];
        if (threadIdx.x < 5) {
            float t = 0.f;
            for (int b = 0; b < 64; b++) t += ws[WS_STATS + b * 5 + threadIdx.x];
            st5[threadIdx.x] = t;
        }
        __syncthreads();
        const float inv_n = 1.0f / (float)N_NODES;
        float m0 = st5[0] * inv_n, m1 = st5[1] * inv_n;
        float v0 = st5[2] * inv_n - m0 * m0;
        float v1 = st5[3] * inv_n - m1 * m1;
        float cv = st5[4] * inv_n - m0 * m1;
        float* par = ws + WS_PAR;
        int j = threadIdx.x;
        if (j < 32) {
            float W0 = w1[j], W1 = w1[32 + j];
            float mu  = m0 * W0 + m1 * W1 + b1[j];
            float var = W0 * W0 * v0 + W1 * W1 * v1 + 2.f * W0 * W1 * cv;
            float is  = rsqrtf(var + 1e-5f) * gamma[j];
            par[j]      = W0 * is;
            par[32 + j] = W1 * is;
            par[64 + j] = (b1[j] - mu) * is + beta[j];
            float u0 = 0.f, ub = 0.f, uf = 0.f;
            for (int k = 0; k < 32; k++) {
                float w2jk = w2[j * 32 + k];
                float vbk = 0.f, vfk = 0.f;
                for (int n = 0; n < 32; n++) {
                    vbk += gbw[k * 32 + n] * wbw[n];
                    vfk += gfw[k * 32 + n] * wfw[n];
                }
                u0 += w2jk * w0w[k];
                ub += w2jk * vbk;
                uf += w2jk * vfk;
            }
            par[96 + j]  = u0;
            par[128 + j] = ub;
            par[160 + j] = uf;
        }
        if (threadIdx.x == 0) {
            float C = w0b[0] + wbb[0] + wfb[0];
            float pc0 = 0.f, pcb = 0.f, pcf = 0.f;
            for (int k = 0; k < 32; k++) {
                float vbk = 0.f, vfk = 0.f;
                for (int n = 0; n < 32; n++) {
                    vbk += gbw[k * 32 + n] * wbw[n];
                    vfk += gfw[k * 32 + n] * wfw[n];
                }
                pc0 += b2[k] * w0w[k];
                pcb += b2[k] * vbk;
                pcf += b2[k] * vfk;
                C   += gbb[k] * wbw[k] + gfb[k] * wfw[k];
            }
            par[192] = C; par[193] = pc0; par[194] = pcb; par[195] = pcf;
        }
    }
}

// ---- launch 4: sortscatter (0..1023) + nodes (1024..1087) +
//      body normalize block-per-row (1088..17471) + face normalize wave-per-row (17472..21567) ----
__global__ void k_big(const int* __restrict__ eib, const int* __restrict__ eif,
                      const float* __restrict__ x, const float* __restrict__ prelu_a,
                      const float* __restrict__ bfeat, const float* __restrict__ ffeat,
                      float* __restrict__ ws) {
    __shared__ float red[4];
    int b = blockIdx.x;
    if (b < 1024) {
        int e = b * 256 + threadIdx.x;          // [0, 2E)
        if (e < N_EDGES) {
            int s = eib[e], d = eib[N_EDGES + e];
            int pos = atomicAdd(&((int*)(ws + WS_CURB))[d], 1);
            ((uint32_t*)(ws + WS_EDGEB))[pos] = (uint32_t)s;
        } else {
            int e2 = e - N_EDGES;
            int s = eif[e2], d = eif[N_EDGES + e2];
            int pos = atomicAdd(&((int*)(ws + WS_CURF))[d], 1);
            ((uint32_t*)(ws + WS_EDGEF))[pos] = (uint32_t)s;
        }
    } else if (b < 1088) {
        int i = (b - 1024) * 256 + threadIdx.x;
        if (i >= N_NODES) return;
        const float* par = ws + WS_PAR;
        float alpha = prelu_a[0];
        float2 v = ((const float2*)x)[i];
        float p0 = par[193], pb = par[194], pf = par[195];
        #pragma unroll
        for (int j = 0; j < 32; j++) {
            float z = v.x * par[j] + v.y * par[32 + j] + par[64 + j];
            float h = z > 0.f ? z : alpha * z;
            p0 += h * par[96 + j];
            pb += h * par[128 + j];
            pf += h * par[160 + j];
        }
        ws[WS_ACC + i] = p0 + par[192];
        ((uint32_t*)(ws + WS_PBF))[i] = pack_h2(pb, pf);
    } else if (b < 17472) {
        // body: one block (256 threads) per row; each thread owns 8 floats
        int row = b - 1088;
        int t = threadIdx.x;
        const float4* F = (const float4*)bfeat + (size_t)row * (DB / 4);
        float4 a0 = F[2 * t];
        float4 a1 = F[2 * t + 1];
        float aa = a0.x * a0.x + a0.y * a0.y + a0.z * a0.z + a0.w * a0.w
                 + a1.x * a1.x + a1.y * a1.y + a1.z * a1.z + a1.w * a1.w;
        #pragma unroll
        for (int off = 32; off; off >>= 1) aa += __shfl_xor(aa, off);
        if ((t & 63) == 0) red[t >> 6] = aa;
        __syncthreads();
        float tot = red[0] + red[1] + red[2] + red[3];
        float inv = rsqrtf(tot + 1e-12f) * FP8_SCALE;
        uint2 o;
        o.x = pack4_fp8(a0.x * inv, a0.y * inv, a0.z * inv, a0.w * inv);
        o.y = pack4_fp8(a1.x * inv, a1.y * inv, a1.z * inv, a1.w * inv);
        ((uint2*)(ws + WS_FNB))[(size_t)row * 256 + t] = o;
    } else {
        // face: wave per row (4 rows per block)
        int idx = (b - 17472) * 4 + (threadIdx.x >> 6);
        int lane = threadIdx.x & 63;
        if (idx >= N_NODES) return;
        const float4* F = (const float4*)ffeat + (size_t)idx * (DF / 4);
        float4 a0 = F[2 * lane];
        float4 a1 = F[2 * lane + 1];
        float aa = a0.x * a0.x + a0.y * a0.y + a0.z * a0.z + a0.w * a0.w
                 + a1.x * a1.x + a1.y * a1.y + a1.z * a1.z + a1.w * a1.w;
        #pragma unroll
        for (int off = 32; off; off >>= 1) aa += __shfl_xor(aa, off);
        float inv = rsqrtf(aa + 1e-12f) * FP8_SCALE;
        uint2 o;
        o.x = pack4_fp8(a0.x * inv, a0.y * inv, a0.z * inv, a0.w * inv);
        o.y = pack4_fp8(a1.x * inv, a1.y * inv, a1.z * inv, a1.w * inv);
        ((uint2*)(ws + WS_FNF))[(size_t)idx * 64 + lane] = o;
    }
}

// ---- launch 5: one wave per DST node; dst row in regs; gather src rows ----
__global__ void k_edge_all(float* __restrict__ ws) {
    int wid  = (int)((blockIdx.x * blockDim.x + threadIdx.x) >> 6);
    int lane = threadIdx.x & 63;
    if (wid < N_NODES) {
        const int* start = (const int*)(ws + WS_STARTB);
        uint32_t* edges  = (uint32_t*)(ws + WS_EDGEB);
        int st = start[wid], en = start[wid + 1];
        if (st >= en) return;
        const uint4* fn = (const uint4*)(ws + WS_FNB);
        const uint4* Dp = fn + (size_t)wid * 128;
        uint4 r0 = Dp[lane], r1 = Dp[lane + 64];
        float dstf[32];
        u32cvt(r0.x, dstf + 0);  u32cvt(r0.y, dstf + 4);
        u32cvt(r0.z, dstf + 8);  u32cvt(r0.w, dstf + 12);
        u32cvt(r1.x, dstf + 16); u32cvt(r1.y, dstf + 20);
        u32cvt(r1.z, dstf + 24); u32cvt(r1.w, dstf + 28);
        float wdeg = 0.f;
        int i = st;
        for (; i + 3 < en; i += 4) {
            uint32_t w0 = edges[i], w1 = edges[i + 1], w2 = edges[i + 2], w3 = edges[i + 3];
            const uint4* A = fn + (size_t)(w0 & 0xFFFFu) * 128;
            const uint4* B = fn + (size_t)(w1 & 0xFFFFu) * 128;
            const uint4* C = fn + (size_t)(w2 & 0xFFFFu) * 128;
            const uint4* E = fn + (size_t)(w3 & 0xFFFFu) * 128;
            uint4 a0 = A[lane], a1 = A[lane + 64];
            uint4 b0 = B[lane], b1 = B[lane + 64];
            uint4 c0 = C[lane], c1 = C[lane + 64];
            uint4 e0 = E[lane], e1 = E[lane + 64];
            float s0 = 0.f, s1 = 0.f, s2 = 0.f, s3 = 0.f;
            s0 = dot16_fp8(a0, dstf, s0); s0 = dot16_fp8(a1, dstf + 16, s0);
            s1 = dot16_fp8(b0, dstf, s1); s1 = dot16_fp8(b1, dstf + 16, s1);
            s2 = dot16_fp8(c0, dstf, s2); s2 = dot16_fp8(c1, dstf + 16, s2);
            s3 = dot16_fp8(e0, dstf, s3); s3 = dot16_fp8(e1, dstf + 16, s3);
            #pragma unroll
            for (int off = 32; off; off >>= 1) {
                s0 += __shfl_xor(s0, off); s1 += __shfl_xor(s1, off);
                s2 += __shfl_xor(s2, off); s3 += __shfl_xor(s3, off);
            }
            if (lane == 0) {
                float m0 = fmaxf(s0, 0.f) * FP8_DESCALE;
                float m1 = fmaxf(s1, 0.f) * FP8_DESCALE;
                float m2 = fmaxf(s2, 0.f) * FP8_DESCALE;
                float m3 = fmaxf(s3, 0.f) * FP8_DESCALE;
                edges[i]     = (w0 & 0xFFFFu) | ((uint32_t)f2h_bits(m0) << 16);
                edges[i + 1] = (w1 & 0xFFFFu) | ((uint32_t)f2h_bits(m1) << 16);
                edges[i + 2] = (w2 & 0xFFFFu) | ((uint32_t)f2h_bits(m2) << 16);
                edges[i + 3] = (w3 & 0xFFFFu) | ((uint32_t)f2h_bits(m3) << 16);
                wdeg += m0 + m1 + m2 + m3;
            }
        }
        for (; i < en; i++) {
            uint32_t w0 = edges[i];
            const uint4* A = fn + (size_t)(w0 & 0xFFFFu) * 128;
            uint4 a0 = A[lane], a1 = A[lane + 64];
            float s0 = 0.f;
            s0 = dot16_fp8(a0, dstf, s0); s0 = dot16_fp8(a1, dstf + 16, s0);
            #pragma unroll
            for (int off = 32; off; off >>= 1) s0 += __shfl_xor(s0, off);
            if (lane == 0) {
                float m0 = fmaxf(s0, 0.f) * FP8_DESCALE;
                edges[i] = (w0 & 0xFFFFu) | ((uint32_t)f2h_bits(m0) << 16);
                wdeg += m0;
            }
        }
        if (lane == 0) ws[WS_DEGB + wid] = 1.f + wdeg;
    } else {
        int nid = wid - N_NODES;
        if (nid >= N_NODES) return;
        const int* start = (const int*)(ws + WS_STARTF);
        uint32_t* edges  = (uint32_t*)(ws + WS_EDGEF);
        int st = start[nid], en = start[nid + 1];
        if (st >= en) return;
        const uint2* fn = (const uint2*)(ws + WS_FNF);
        uint2 sv = fn[(size_t)nid * 64 + lane];
        float dstf[8];
        u32cvt(sv.x, dstf); u32cvt(sv.y, dstf + 4);
        float wdeg = 0.f;
        int i = st;
        for (; i + 3 < en; i += 4) {
            uint32_t w0 = edges[i], w1 = edges[i + 1], w2 = edges[i + 2], w3 = edges[i + 3];
            uint2 r0 = fn[(size_t)(w0 & 0xFFFFu) * 64 + lane];
            uint2 r1 = fn[(size_t)(w1 & 0xFFFFu) * 64 + lane];
            uint2 r2 = fn[(size_t)(w2 & 0xFFFFu) * 64 + lane];
            uint2 r3 = fn[(size_t)(w3 & 0xFFFFu) * 64 + lane];
            float c0 = u32dot(r0.y, dstf + 4, u32dot(r0.x, dstf, 0.f));
            float c1 = u32dot(r1.y, dstf + 4, u32dot(r1.x, dstf, 0.f));
            float c2 = u32dot(r2.y, dstf + 4, u32dot(r2.x, dstf, 0.f));
            float c3 = u32dot(r3.y, dstf + 4, u32dot(r3.x, dstf, 0.f));
            #pragma unroll
            for (int off = 32; off; off >>= 1) {
                c0 += __shfl_xor(c0, off); c1 += __shfl_xor(c1, off);
                c2 += __shfl_xor(c2, off); c3 += __shfl_xor(c3, off);
            }
            if (lane == 0) {
                float m0 = fmaxf(c0, 0.f) * FP8_DESCALE;
                float m1 = fmaxf(c1, 0.f) * FP8_DESCALE;
                float m2 = fmaxf(c2, 0.f) * FP8_DESCALE;
                float m3 = fmaxf(c3, 0.f) * FP8_DESCALE;
                edges[i]     = (w0 & 0xFFFFu) | ((uint32_t)f2h_bits(m0) << 16);
                edges[i + 1] = (w1 & 0xFFFFu) | ((uint32_t)f2h_bits(m1) << 16);
                edges[i + 2] = (w2 & 0xFFFFu) | ((uint32_t)f2h_bits(m2) << 16);
                edges[i + 3] = (w3 & 0xFFFFu) | ((uint32_t)f2h_bits(m3) << 16);
                wdeg += m0 + m1 + m2 + m3;
            }
        }
        for (; i < en; i++) {
            uint32_t w0 = edges[i];
            uint2 r0 = fn[(size_t)(w0 & 0xFFFFu) * 64 + lane];
            float c0 = u32dot(r0.y, dstf + 4, u32dot(r0.x, dstf, 0.f));
            #pragma unroll
            for (int off = 32; off; off >>= 1) c0 += __shfl_xor(c0, off);
            if (lane == 0) {
                float m0 = fmaxf(c0, 0.f) * FP8_DESCALE;
                edges[i] = (w0 & 0xFFFFu) | ((uint32_t)f2h_bits(m0) << 16);
                wdeg += m0;
            }
        }
        if (lane == 0) ws[WS_DEGF + nid] = 1.f + wdeg;
    }
}

// ---- launch 6: thread-per-(dst,graph) pull; graph-1 partial joins via LDS ----
__global__ void k_out(float* __restrict__ out, const float* __restrict__ ws) {
    __shared__ float part[128];
    int half = threadIdx.x >> 7;              // wave-uniform (waves 0,1 vs 2,3)
    int li   = threadIdx.x & 127;
    int i    = blockIdx.x * 128 + li;
    const uint32_t* pk = (const uint32_t*)(ws + WS_PBF);
    int g = half;
    const int* st       = (const int*)(ws + (g ? WS_STARTF : WS_STARTB));
    const uint32_t* eg  = (const uint32_t*)(ws + (g ? WS_EDGEF : WS_EDGEB));
    const float* deg    = ws + (g ? WS_DEGF : WS_DEGB);
    float sum = 0.f;
    int e0 = st[i], e1 = st[i + 1];
    for (int e = e0; e < e1; e++) {
        uint32_t w = eg[e];
        float sm = h_bits2f((uint16_t)(w >> 16));
        if (sm > 0.f) {
            int s = (int)(w & 0xFFFFu);
            uint32_t ps = pk[s];
            float p = h_bits2f(g ? (uint16_t)(ps >> 16) : (uint16_t)(ps & 0xFFFFu));
            sum += rsqrtf(fmaxf(deg[s], 1e-6f)) * sm * p;
        }
    }
    float dn = rsqrtf(fmaxf(deg[i], 1e-6f));
    uint32_t pme = pk[i];
    float pv = h_bits2f(g ? (uint16_t)(pme >> 16) : (uint16_t)(pme & 0xFFFFu));
    float contrib = dn * (dn * pv + sum);
    if (half == 1) part[li] = contrib;
    __syncthreads();
    if (half == 0) out[i] = ws[WS_ACC + i] + contrib + part[li];
}

extern "C" void kernel_launch(void* const* d_in, const int* in_sizes, int n_in,
                              void* d_out, int out_size, void* d_ws, size_t ws_size,
                              hipStream_t stream) {
    const float* x     = (const float*)d_in[0];
    const float* bfeat = (const float*)d_in[1];
    const float* ffeat = (const float*)d_in[2];
    const int*   eib   = (const int*)d_in[3];
    const int*   eif   = (const int*)d_in[4];
    const float* w1    = (const float*)d_in[5];
    const float* b1    = (const float*)d_in[6];
    const float* gam   = (const float*)d_in[7];
    const float* bet   = (const float*)d_in[8];
    const float* pa    = (const float*)d_in[9];
    const float* w2    = (const float*)d_in[10];
    const float* b2    = (const float*)d_in[11];
    const float* w0w   = (const float*)d_in[12];
    const float* w0b   = (const float*)d_in[13];
    const float* gbw   = (const float*)d_in[14];
    const float* gbb   = (const float*)d_in[15];
    const float* gfw   = (const float*)d_in[16];
    const float* gfb   = (const float*)d_in[17];
    const float* wbw   = (const float*)d_in[18];
    const float* wbb   = (const float*)d_in[19];
    const float* wfw   = (const float*)d_in[20];
    const float* wfb   = (const float*)d_in[21];

    float* ws  = (float*)d_ws;
    float* out = (float*)d_out;

    k_pre<<<dim3(192), dim3(256), 0, stream>>>(x, ws);
    k_hist<<<dim3(1024), dim3(256), 0, stream>>>(eib, eif, ws);
    k_scan<<<dim3(2), dim3(256), 0, stream>>>(w1, b1, gam, bet, w2, b2, w0w, w0b,
                                              gbw, gbb, gfw, gfb, wbw, wbb, wfw, wfb, ws);
    k_big<<<dim3(21568), dim3(256), 0, stream>>>(eib, eif, x, pa, bfeat, ffeat, ws);
    k_edge_all<<<dim3(2 * N_NODES / 4), dim3(256), 0, stream>>>(ws);
    k_out<<<dim3(N_NODES / 128), dim3(256), 0, stream>>>(out, ws);
}